// Round 1
// baseline (1809.115 us; speedup 1.0000x reference)
//
#include <hip/hip_runtime.h>
#include <math.h>

// ---------------------------------------------------------------------------
// IsgnBeatMeasEncoder — full-network HIP implementation (round 0: correctness)
// N=1024 notes, E=10 edge types, S=320 state, SEC=128 updated section.
// Fixed structure: beat = i/4, measure = i/16, beat_to_meas = b/4.
// Workspace required: ~31 MB (see layout in kernel_launch).
// ---------------------------------------------------------------------------

#define NN    1024
#define EE    10
#define INDIM 78
#define NOTED 128
#define BEATD 64
#define MEASD 32
#define SS    320
#define SECD  128
#define NB    256
#define NM    64
#define CAP   64     // max nonzeros per adjacency column (mean ~10.2)

__device__ __forceinline__ float sigmoidf_(float x){ return 1.f/(1.f + expf(-x)); }

// ---------------- note_fc: x0 = tanh(nodes @ W + b); notes_hidden = [0(192) | x0] ----
__global__ void k_note_fc(const float* __restrict__ nodes, const float* __restrict__ W,
                          const float* __restrict__ b, float* __restrict__ nhid){
    int n = blockIdx.x, s = threadIdx.x;           // 128 threads
    __shared__ float xrow[INDIM];
    if (s < INDIM) xrow[s] = nodes[n*INDIM + s];
    __syncthreads();
    float acc = b[s];
    for (int k = 0; k < INDIM; ++k) acc += xrow[k]*W[k*NOTED + s];
    nhid[n*SS + 192 + s] = tanhf(acc);
    nhid[n*SS + s] = 0.f;
    if (s < 64) nhid[n*SS + 128 + s] = 0.f;
}

// ---------------- CSR build: for each (e, column n) list of source rows m ----------
__global__ void k_csr_build(const float* __restrict__ adj, int* __restrict__ cnt,
                            int* __restrict__ idx){
    int em = blockIdx.x;                   // e*NN + m  (row of adj[e])
    int e = em / NN, m = em % NN;
    const float* row = adj + (size_t)em * NN;
    for (int n = threadIdx.x; n < NN; n += blockDim.x){
        if (row[n] != 0.f){
            int p = atomicAdd(&cnt[e*NN + n], 1);
            if (p < CAP) idx[((size_t)e*NN + n)*CAP + p] = m;
        }
    }
}

// ---------------- act[e,n,f] = sum over column list of x[m,f] ----------------------
__global__ void k_gather_act(const float* __restrict__ x, const int* __restrict__ cnt,
                             const int* __restrict__ idx, float* __restrict__ act){
    int en = blockIdx.x, f = threadIdx.x;  // 320 threads
    int c = cnt[en]; if (c > CAP) c = CAP;
    const int* lst = idx + (size_t)en*CAP;
    float acc = 0.f;
    for (int j = 0; j < c; ++j) acc += x[lst[j]*SS + f];
    act[(size_t)en*SS + f] = acc;
}

// ---------------- gate GEMM: part[z][n][g*128+s] = sum_{e in pair z, f} act*w -------
// M=1024, K=3200 (split 5x640), Nout=3x128. Tile 64x128, 256 thr, 8x4 per thread.
__global__ __launch_bounds__(256) void k_gate_gemm(const float* __restrict__ act,
        const float* __restrict__ wz, const float* __restrict__ wr,
        const float* __restrict__ wh, float* __restrict__ part){
    __shared__ float A[32*76];     // [kk][row], pad 76
    __shared__ float B[32*132];    // [kk][col], pad 132
    int nt = blockIdx.x, g = blockIdx.y, z = blockIdx.z;
    const float* W = (g==0) ? wz : ((g==1) ? wr : wh);
    int tid = threadIdx.x;
    int tx = tid & 31;             // cols tx*4 .. +3
    int ty = tid >> 5;             // rows ty*8 .. +7
    float acc[8][4];
    #pragma unroll
    for (int i=0;i<8;i++){ acc[i][0]=0.f; acc[i][1]=0.f; acc[i][2]=0.f; acc[i][3]=0.f; }
    for (int eh = 0; eh < 2; ++eh){
        int e = z*2 + eh;
        const float* Ae = act + (size_t)e*NN*SS + (size_t)nt*64*SS;
        const float* We = W   + (size_t)e*SS*SECD;
        for (int kc = 0; kc < SS; kc += 32){
            #pragma unroll
            for (int i=0;i<2;i++){                 // A: 64 rows x 32 k
                int lin4 = tid + i*256;            // 512 float4
                int r  = lin4 >> 3;
                int k4 = (lin4 & 7) << 2;
                float4 v = *(const float4*)(Ae + r*SS + kc + k4);
                A[(k4+0)*76 + r] = v.x; A[(k4+1)*76 + r] = v.y;
                A[(k4+2)*76 + r] = v.z; A[(k4+3)*76 + r] = v.w;
            }
            #pragma unroll
            for (int i=0;i<4;i++){                 // B: 32 k x 128 cols
                int lin4 = tid + i*256;            // 1024 float4
                int kk = lin4 >> 5;
                int c4 = (lin4 & 31) << 2;
                *((float4*)(B + kk*132 + c4)) = *(const float4*)(We + (kc+kk)*SECD + c4);
            }
            __syncthreads();
            #pragma unroll 8
            for (int k=0;k<32;k++){
                float4 a0 = *(const float4*)(A + k*76 + ty*8);
                float4 a1 = *(const float4*)(A + k*76 + ty*8 + 4);
                float4 b0 = *(const float4*)(B + k*132 + tx*4);
                float av[8] = {a0.x,a0.y,a0.z,a0.w,a1.x,a1.y,a1.z,a1.w};
                float bv[4] = {b0.x,b0.y,b0.z,b0.w};
                #pragma unroll
                for (int i=0;i<8;i++)
                    #pragma unroll
                    for (int j=0;j<4;j++) acc[i][j] += av[i]*bv[j];
            }
            __syncthreads();
        }
    }
    float* P = part + ((size_t)z*NN + (size_t)nt*64)*384 + g*SECD;
    #pragma unroll
    for (int i=0;i<8;i++){
        int r = ty*8 + i;
        *(float4*)(P + (size_t)r*384 + tx*4) =
            make_float4(acc[i][0],acc[i][1],acc[i][2],acc[i][3]);
    }
}

// ---------------- GRU update (in place on x's last 128 cols), 4 notes/block --------
__global__ void k_gru(float* __restrict__ x, const float* __restrict__ part,
        const float* __restrict__ uz, const float* __restrict__ ur, const float* __restrict__ uh,
        const float* __restrict__ bz, const float* __restrict__ br, const float* __restrict__ bh){
    int n0 = blockIdx.x*4, s = threadIdx.x;        // 128 threads
    __shared__ float xs[4][SECD], rx[4][SECD];
    #pragma unroll
    for (int j=0;j<4;j++) xs[j][s] = x[(n0+j)*SS + 192 + s];
    __syncthreads();
    float mz[4]={0,0,0,0}, mr[4]={0,0,0,0}, mh[4]={0,0,0,0};
    for (int sp=0; sp<5; sp++){
        const float* Pp = part + ((size_t)sp*NN + n0)*384;
        #pragma unroll
        for (int j=0;j<4;j++){
            mz[j] += Pp[j*384 + s];
            mr[j] += Pp[j*384 + 128 + s];
            mh[j] += Pp[j*384 + 256 + s];
        }
    }
    float dz[4]={0,0,0,0}, dr[4]={0,0,0,0};
    for (int k=0;k<SECD;k++){
        float wz_ = uz[k*SECD + s], wr_ = ur[k*SECD + s];
        #pragma unroll
        for (int j=0;j<4;j++){ float xv = xs[j][k]; dz[j] += xv*wz_; dr[j] += xv*wr_; }
    }
    float zz[4], rr[4];
    #pragma unroll
    for (int j=0;j<4;j++){
        zz[j] = sigmoidf_(mz[j] + dz[j] + bz[s]);
        rr[j] = sigmoidf_(mr[j] + dr[j] + br[s]);
        rx[j][s] = rr[j]*xs[j][s];
    }
    __syncthreads();
    float dh[4]={0,0,0,0};
    for (int k=0;k<SECD;k++){
        float wh_ = uh[k*SECD + s];
        #pragma unroll
        for (int j=0;j<4;j++) dh[j] += rx[j][k]*wh_;
    }
    #pragma unroll
    for (int j=0;j<4;j++){
        float h = tanhf(mh[j] + dh[j] + bh[s]);
        x[(n0+j)*SS + 192 + s] = (1.f - zz[j])*xs[j][s] + rr[j]*h;
    }
}

// ---------------- nb = relu(nh @ gb_w + gb_b), 8 notes/block -----------------------
__global__ void k_gb(const float* __restrict__ nh, const float* __restrict__ W,
                     const float* __restrict__ b, float* __restrict__ nb){
    int n0 = blockIdx.x*8, s = threadIdx.x;        // 320 threads
    __shared__ float xr[8][SS];
    #pragma unroll
    for (int j=0;j<8;j++) xr[j][s] = nh[(n0+j)*SS + s];
    __syncthreads();
    float acc[8]; float bv = b[s];
    #pragma unroll
    for (int j=0;j<8;j++) acc[j] = bv;
    for (int k=0;k<SS;k++){
        float w = W[k*SS + s];
        #pragma unroll
        for (int j=0;j<8;j++) acc[j] += xr[j][k]*w;
    }
    #pragma unroll
    for (int j=0;j<8;j++) nb[(n0+j)*SS + s] = fmaxf(acc[j], 0.f);
}

// ---------------- cat = [nh[:,192:320] | nh2[:,192:320]] ---------------------------
__global__ void k_build_cat(const float* __restrict__ nh, const float* __restrict__ nh2,
                            float* __restrict__ cat){
    int m = blockIdx.x, s = threadIdx.x;           // 256 threads
    cat[m*256 + s] = (s < 128) ? nh[m*SS + 192 + s] : nh2[m*SS + 64 + s];
}

// ---------------- attention sim: a=tanh(x@W+b); sim[m,h]=dot(a_head, c_head) -------
template<int D, int HD>
__global__ void k_att_sim(const float* __restrict__ x, const float* __restrict__ W,
                          const float* __restrict__ b, const float* __restrict__ c,
                          float* __restrict__ sim){
    int m0 = blockIdx.x*4, s = threadIdx.x;        // D threads
    __shared__ float xr[4][D];
    #pragma unroll
    for (int j=0;j<4;j++) xr[j][s] = x[(m0+j)*D + s];
    __syncthreads();
    float bias = b[s];
    float acc[4] = {bias,bias,bias,bias};
    for (int k=0;k<D;k++){
        float w = W[k*D + s];
        #pragma unroll
        for (int j=0;j<4;j++) acc[j] += xr[j][k]*w;
    }
    float cv = c[s];
    int h = s / HD;
    #pragma unroll
    for (int j=0;j<4;j++){
        float p = tanhf(acc[j])*cv;
        #pragma unroll
        for (int off=HD/2; off>0; off>>=1) p += __shfl_down(p, off);
        if ((s & (HD-1)) == 0) sim[(m0+j)*8 + h] = p;
    }
}

// ---------------- segment softmax (groups of 4 contiguous) + weighted sum ----------
template<int D, int HD>
__global__ void k_att_seg(const float* __restrict__ x, const float* __restrict__ sim,
                          float* __restrict__ out){
    int g = blockIdx.x, s = threadIdx.x;           // D threads
    __shared__ float wgt[4][8];
    if (s < 8){
        float v0 = sim[(g*4+0)*8+s], v1 = sim[(g*4+1)*8+s];
        float v2 = sim[(g*4+2)*8+s], v3 = sim[(g*4+3)*8+s];
        float mx = fmaxf(fmaxf(v0,v1), fmaxf(v2,v3));
        float e0 = expf(v0-mx), e1 = expf(v1-mx), e2 = expf(v2-mx), e3 = expf(v3-mx);
        float den = e0+e1+e2+e3;
        wgt[0][s]=e0/den; wgt[1][s]=e1/den; wgt[2][s]=e2/den; wgt[3][s]=e3/den;
    }
    __syncthreads();
    int h = s / HD;
    float o = 0.f;
    #pragma unroll
    for (int j=0;j<4;j++) o += x[(g*4+j)*D + s]*wgt[j][h];
    out[g*D + s] = o;
}

// ---------------- LSTM input pre-GEMM: g[t][gi] = b[gi] + wi[gi,:].x[t,:] ----------
template<int TIN, int G4>
__global__ void k_lstm_pre(const float* __restrict__ x,
        const float* __restrict__ wi_f, const float* __restrict__ b_f,
        const float* __restrict__ wi_b, const float* __restrict__ b_b,
        float* __restrict__ gf, float* __restrict__ gbo){
    int t0 = blockIdx.x*4, gi = threadIdx.x;       // G4 threads
    const float* wi = blockIdx.y ? wi_b : wi_f;
    const float* bb = blockIdx.y ? b_b  : b_f;
    float* go       = blockIdx.y ? gbo  : gf;
    __shared__ float xr[4][TIN];
    #pragma unroll
    for (int j=0;j<4;j++)
        for (int k=gi; k<TIN; k+=G4) xr[j][k] = x[(t0+j)*TIN + k];
    __syncthreads();
    float bv = bb[gi];
    float acc[4] = {bv,bv,bv,bv};
    const float* wrow = wi + (size_t)gi*TIN;
    for (int k=0;k<TIN;k++){
        float w = wrow[k];
        #pragma unroll
        for (int j=0;j<4;j++) acc[j] += xr[j][k]*w;
    }
    #pragma unroll
    for (int j=0;j<4;j++) go[(t0+j)*G4 + gi] = acc[j];
}

// ---------------- LSTM recurrence: block per direction, 4 lanes per gate row -------
template<int H, int T>
__global__ __launch_bounds__(1024) void k_lstm_rec(
        const float* __restrict__ gin_f, const float* __restrict__ wh_f,
        const float* __restrict__ gin_b, const float* __restrict__ wh_b,
        float* __restrict__ hid /* [T][2H] */){
    const int KS = H/4;
    int dir = blockIdx.x;
    const float* gin = dir ? gin_b : gin_f;
    const float* wh  = dir ? wh_b  : wh_f;
    int tid = threadIdx.x;             // = gi*4 + q, gi in [0,4H)
    int gi = tid >> 2, q = tid & 3;
    float wreg[16];
    #pragma unroll
    for (int k=0;k<KS;k++) wreg[k] = wh[(size_t)gi*H + q*KS + k];
    __shared__ float hs[H], cs[H], gsum[4*H];
    if (tid < H){ hs[tid] = 0.f; cs[tid] = 0.f; }
    __syncthreads();
    for (int step=0; step<T; step++){
        int t = dir ? (T-1-step) : step;
        float a = 0.f;
        #pragma unroll
        for (int k=0;k<KS;k++) a += wreg[k]*hs[q*KS + k];
        a += __shfl_xor(a, 1);
        a += __shfl_xor(a, 2);
        if (q == 0) gsum[gi] = a + gin[t*4*H + gi];
        __syncthreads();
        if (tid < H){
            int j = tid;
            float ig = gsum[j], fg = gsum[H+j], gg = gsum[2*H+j], og = gsum[3*H+j];
            float cn = sigmoidf_(fg)*cs[j] + sigmoidf_(ig)*tanhf(gg);
            cs[j] = cn;
            float hn = sigmoidf_(og)*tanhf(cn);
            hs[j] = hn;
            hid[t*2*H + dir*H + j] = hn;
        }
        __syncthreads();
    }
}

// ---------------- rebuild notes_hidden = [beat_span | meas_span | nh_sec] ----------
__global__ void k_spans(float* __restrict__ nhid, const float* __restrict__ bh,
                        const float* __restrict__ mh, const float* __restrict__ nh,
                        const int* __restrict__ bn, const int* __restrict__ mn){
    int n = blockIdx.x, s = threadIdx.x;           // 320 threads
    float v;
    if (s < 128)      v = bh[bn[n]*128 + s];
    else if (s < 192) v = mh[mn[n]*64 + (s-128)];
    else              v = nh[n*SS + s];
    nhid[n*SS + s] = v;
}

// ---------------- final output = [notes_hidden(320) | nh2_sec(128)] ----------------
__global__ void k_final(const float* __restrict__ nhid, const float* __restrict__ nh2,
                        float* __restrict__ out){
    int n = blockIdx.x, s = threadIdx.x;           // 448 threads
    out[n*448 + s] = (s < 320) ? nhid[n*SS + s] : nh2[n*SS + 192 + (s-320)];
}

// ===========================================================================
extern "C" void kernel_launch(void* const* d_in, const int* in_sizes, int n_in,
                              void* d_out, int out_size, void* d_ws, size_t ws_size,
                              hipStream_t stream) {
    // --- inputs (setup_inputs dict order) ---
    const float* nodes    = (const float*)d_in[0];
    const float* adj      = (const float*)d_in[1];
    const int*   bn       = (const int*)  d_in[2];
    const int*   mn       = (const int*)  d_in[3];
    const float* fc_w     = (const float*)d_in[6];
    const float* fc_b     = (const float*)d_in[7];
    const float* g_wz[2]  = {(const float*)d_in[8],  (const float*)d_in[17]};
    const float* g_wr[2]  = {(const float*)d_in[9],  (const float*)d_in[18]};
    const float* g_wh[2]  = {(const float*)d_in[10], (const float*)d_in[19]};
    const float* g_uz[2]  = {(const float*)d_in[11], (const float*)d_in[20]};
    const float* g_ur[2]  = {(const float*)d_in[12], (const float*)d_in[21]};
    const float* g_uh[2]  = {(const float*)d_in[13], (const float*)d_in[22]};
    const float* g_bz[2]  = {(const float*)d_in[14], (const float*)d_in[23]};
    const float* g_br[2]  = {(const float*)d_in[15], (const float*)d_in[24]};
    const float* g_bh[2]  = {(const float*)d_in[16], (const float*)d_in[25]};
    const float* gb_w     = (const float*)d_in[26];
    const float* gb_b     = (const float*)d_in[27];
    const float* batt_w   = (const float*)d_in[28];
    const float* batt_b   = (const float*)d_in[29];
    const float* batt_c   = (const float*)d_in[30];
    const float* matt_w   = (const float*)d_in[31];
    const float* matt_b   = (const float*)d_in[32];
    const float* matt_c   = (const float*)d_in[33];
    const float* bwi_f    = (const float*)d_in[34];
    const float* bwh_f    = (const float*)d_in[35];
    const float* bb_f     = (const float*)d_in[36];
    const float* bwi_b    = (const float*)d_in[37];
    const float* bwh_b    = (const float*)d_in[38];
    const float* bb_b     = (const float*)d_in[39];
    const float* mwi_f    = (const float*)d_in[40];
    const float* mwh_f    = (const float*)d_in[41];
    const float* mb_f     = (const float*)d_in[42];
    const float* mwi_b    = (const float*)d_in[43];
    const float* mwh_b    = (const float*)d_in[44];
    const float* mb_b     = (const float*)d_in[45];
    float* out = (float*)d_out;

    // --- workspace layout (floats; total ~31 MB) ---
    float* W_   = (float*)d_ws;
    float* nhid = W_;                       // 1024*320
    float* nh   = nhid + 327680;            // 1024*320
    float* nh2  = nh   + 327680;            // 1024*320
    float* nb   = nh2  + 327680;            // 1024*320
    float* act  = nb   + 327680;            // 10*1024*320
    float* part = act  + 3276800;           // 5*1024*384
    float* cat  = part + 1966080;           // 1024*256
    float* sim  = cat  + 262144;            // 1024*8
    float* beat_nodes = sim + 8192;         // 256*256
    float* bgf  = beat_nodes + 65536;       // 256*256
    float* bgb  = bgf  + 65536;             // 256*256
    float* beat_hidden = bgb + 65536;       // 256*128
    float* msim = beat_hidden + 32768;      // 256*8
    float* meas_nodes = msim + 2048;        // 64*128
    float* mgf  = meas_nodes + 8192;        // 64*128
    float* mgb  = mgf  + 8192;              // 64*128
    float* meas_hidden = mgb + 8192;        // 64*64
    int*   cnt  = (int*)(meas_hidden + 4096);  // 10*1024
    int*   idx  = cnt + 10240;                  // 10*1024*64

    // --- adjacency -> column lists (once per launch; ws re-poisoned each call) ---
    hipMemsetAsync(cnt, 0, EE*NN*sizeof(int), stream);
    k_csr_build<<<EE*NN, 256, 0, stream>>>(adj, cnt, idx);

    // --- initial notes_hidden ---
    k_note_fc<<<NN, 128, 0, stream>>>(nodes, fc_w, fc_b, nhid);

    for (int si = 0; si < 2; ++si){
        // ---- nh = gated_graph(notes_hidden, g1) ----
        hipMemcpyAsync(nh, nhid, (size_t)NN*SS*sizeof(float), hipMemcpyDeviceToDevice, stream);
        for (int it = 0; it < 2; ++it){
            k_gather_act<<<EE*NN, SS, 0, stream>>>(nh, cnt, idx, act);
            k_gate_gemm<<<dim3(16,3,5), 256, 0, stream>>>(act, g_wz[0], g_wr[0], g_wh[0], part);
            k_gru<<<NN/4, 128, 0, stream>>>(nh, part, g_uz[0], g_ur[0], g_uh[0],
                                            g_bz[0], g_br[0], g_bh[0]);
        }
        // ---- nb = relu(nh @ gb_w + gb_b) ----
        k_gb<<<NN/8, SS, 0, stream>>>(nh, gb_w, gb_b, nb);
        // ---- nh2 = gated_graph(nb, g2) ----
        hipMemcpyAsync(nh2, nb, (size_t)NN*SS*sizeof(float), hipMemcpyDeviceToDevice, stream);
        for (int it = 0; it < 2; ++it){
            k_gather_act<<<EE*NN, SS, 0, stream>>>(nh2, cnt, idx, act);
            k_gate_gemm<<<dim3(16,3,5), 256, 0, stream>>>(act, g_wz[1], g_wr[1], g_wh[1], part);
            k_gru<<<NN/4, 128, 0, stream>>>(nh2, part, g_uz[1], g_ur[1], g_uh[1],
                                            g_bz[1], g_br[1], g_bh[1]);
        }
        // ---- beat attention over cat = [nh_sec | nh2_sec] ----
        k_build_cat<<<NN, 256, 0, stream>>>(nh, nh2, cat);
        k_att_sim<256,32><<<NN/4, 256, 0, stream>>>(cat, batt_w, batt_b, batt_c, sim);
        k_att_seg<256,32><<<NB, 256, 0, stream>>>(cat, sim, beat_nodes);
        // ---- beat BiLSTM (hidden 64, T=256) ----
        k_lstm_pre<256,256><<<dim3(NB/4,2), 256, 0, stream>>>(beat_nodes, bwi_f, bb_f,
                                                              bwi_b, bb_b, bgf, bgb);
        k_lstm_rec<64,256><<<2, 1024, 0, stream>>>(bgf, bwh_f, bgb, bwh_b, beat_hidden);
        // ---- measure attention over beat_hidden ----
        k_att_sim<128,16><<<NB/4, 128, 0, stream>>>(beat_hidden, matt_w, matt_b, matt_c, msim);
        k_att_seg<128,16><<<NM, 128, 0, stream>>>(beat_hidden, msim, meas_nodes);
        // ---- measure BiLSTM (hidden 32, T=64) ----
        k_lstm_pre<128,128><<<dim3(NM/4,2), 128, 0, stream>>>(meas_nodes, mwi_f, mb_f,
                                                              mwi_b, mb_b, mgf, mgb);
        k_lstm_rec<32,64><<<2, 512, 0, stream>>>(mgf, mwh_f, mgb, mwh_b, meas_hidden);
        // ---- notes_hidden = [beat_span | meas_span | nh_sec] ----
        k_spans<<<NN, SS, 0, stream>>>(nhid, beat_hidden, meas_hidden, nh, bn, mn);
    }
    // ---- final = [notes_hidden | nh2_sec] ----
    k_final<<<NN, 448, 0, stream>>>(nhid, nh2, out);
}

// Round 2
// 1806.588 us; speedup vs baseline: 1.0014x; 1.0014x over previous
//
#include <hip/hip_runtime.h>
#include <math.h>

// ---------------------------------------------------------------------------
// IsgnBeatMeasEncoder — round 1: LSTM recurrence rewrite (reg weights, 4H thr)
// N=1024 notes, E=10 edge types, S=320 state, SEC=128 updated section.
// Fixed structure: beat = i/4, measure = i/16, beat_to_meas = b/4.
// Workspace required: ~31 MB (see layout in kernel_launch).
// ---------------------------------------------------------------------------

#define NN    1024
#define EE    10
#define INDIM 78
#define NOTED 128
#define BEATD 64
#define MEASD 32
#define SS    320
#define SECD  128
#define NB    256
#define NM    64
#define CAP   64     // max nonzeros per adjacency column (mean ~10.2)

__device__ __forceinline__ float sigmoidf_(float x){ return 1.f/(1.f + expf(-x)); }

// ---------------- note_fc: x0 = tanh(nodes @ W + b); notes_hidden = [0(192) | x0] ----
__global__ void k_note_fc(const float* __restrict__ nodes, const float* __restrict__ W,
                          const float* __restrict__ b, float* __restrict__ nhid){
    int n = blockIdx.x, s = threadIdx.x;           // 128 threads
    __shared__ float xrow[INDIM];
    if (s < INDIM) xrow[s] = nodes[n*INDIM + s];
    __syncthreads();
    float acc = b[s];
    for (int k = 0; k < INDIM; ++k) acc += xrow[k]*W[k*NOTED + s];
    nhid[n*SS + 192 + s] = tanhf(acc);
    nhid[n*SS + s] = 0.f;
    if (s < 64) nhid[n*SS + 128 + s] = 0.f;
}

// ---------------- CSR build: for each (e, column n) list of source rows m ----------
__global__ void k_csr_build(const float* __restrict__ adj, int* __restrict__ cnt,
                            int* __restrict__ idx){
    int em = blockIdx.x;                   // e*NN + m  (row of adj[e])
    int e = em / NN, m = em % NN;
    const float* row = adj + (size_t)em * NN;
    for (int n = threadIdx.x; n < NN; n += blockDim.x){
        if (row[n] != 0.f){
            int p = atomicAdd(&cnt[e*NN + n], 1);
            if (p < CAP) idx[((size_t)e*NN + n)*CAP + p] = m;
        }
    }
}

// ---------------- act[e,n,f] = sum over column list of x[m,f] ----------------------
__global__ void k_gather_act(const float* __restrict__ x, const int* __restrict__ cnt,
                             const int* __restrict__ idx, float* __restrict__ act){
    int en = blockIdx.x, f = threadIdx.x;  // 320 threads
    int c = cnt[en]; if (c > CAP) c = CAP;
    const int* lst = idx + (size_t)en*CAP;
    float acc = 0.f;
    for (int j = 0; j < c; ++j) acc += x[lst[j]*SS + f];
    act[(size_t)en*SS + f] = acc;
}

// ---------------- gate GEMM: part[z][n][g*128+s] = sum_{e in pair z, f} act*w -------
// M=1024, K=3200 (split 5x640), Nout=3x128. Tile 64x128, 256 thr, 8x4 per thread.
__global__ __launch_bounds__(256) void k_gate_gemm(const float* __restrict__ act,
        const float* __restrict__ wz, const float* __restrict__ wr,
        const float* __restrict__ wh, float* __restrict__ part){
    __shared__ float A[32*76];     // [kk][row], pad 76
    __shared__ float B[32*132];    // [kk][col], pad 132
    int nt = blockIdx.x, g = blockIdx.y, z = blockIdx.z;
    const float* W = (g==0) ? wz : ((g==1) ? wr : wh);
    int tid = threadIdx.x;
    int tx = tid & 31;             // cols tx*4 .. +3
    int ty = tid >> 5;             // rows ty*8 .. +7
    float acc[8][4];
    #pragma unroll
    for (int i=0;i<8;i++){ acc[i][0]=0.f; acc[i][1]=0.f; acc[i][2]=0.f; acc[i][3]=0.f; }
    for (int eh = 0; eh < 2; ++eh){
        int e = z*2 + eh;
        const float* Ae = act + (size_t)e*NN*SS + (size_t)nt*64*SS;
        const float* We = W   + (size_t)e*SS*SECD;
        for (int kc = 0; kc < SS; kc += 32){
            #pragma unroll
            for (int i=0;i<2;i++){                 // A: 64 rows x 32 k
                int lin4 = tid + i*256;            // 512 float4
                int r  = lin4 >> 3;
                int k4 = (lin4 & 7) << 2;
                float4 v = *(const float4*)(Ae + r*SS + kc + k4);
                A[(k4+0)*76 + r] = v.x; A[(k4+1)*76 + r] = v.y;
                A[(k4+2)*76 + r] = v.z; A[(k4+3)*76 + r] = v.w;
            }
            #pragma unroll
            for (int i=0;i<4;i++){                 // B: 32 k x 128 cols
                int lin4 = tid + i*256;            // 1024 float4
                int kk = lin4 >> 5;
                int c4 = (lin4 & 31) << 2;
                *((float4*)(B + kk*132 + c4)) = *(const float4*)(We + (kc+kk)*SECD + c4);
            }
            __syncthreads();
            #pragma unroll 8
            for (int k=0;k<32;k++){
                float4 a0 = *(const float4*)(A + k*76 + ty*8);
                float4 a1 = *(const float4*)(A + k*76 + ty*8 + 4);
                float4 b0 = *(const float4*)(B + k*132 + tx*4);
                float av[8] = {a0.x,a0.y,a0.z,a0.w,a1.x,a1.y,a1.z,a1.w};
                float bv[4] = {b0.x,b0.y,b0.z,b0.w};
                #pragma unroll
                for (int i=0;i<8;i++)
                    #pragma unroll
                    for (int j=0;j<4;j++) acc[i][j] += av[i]*bv[j];
            }
            __syncthreads();
        }
    }
    float* P = part + ((size_t)z*NN + (size_t)nt*64)*384 + g*SECD;
    #pragma unroll
    for (int i=0;i<8;i++){
        int r = ty*8 + i;
        *(float4*)(P + (size_t)r*384 + tx*4) =
            make_float4(acc[i][0],acc[i][1],acc[i][2],acc[i][3]);
    }
}

// ---------------- GRU update (in place on x's last 128 cols), 4 notes/block --------
__global__ void k_gru(float* __restrict__ x, const float* __restrict__ part,
        const float* __restrict__ uz, const float* __restrict__ ur, const float* __restrict__ uh,
        const float* __restrict__ bz, const float* __restrict__ br, const float* __restrict__ bh){
    int n0 = blockIdx.x*4, s = threadIdx.x;        // 128 threads
    __shared__ float xs[4][SECD], rx[4][SECD];
    #pragma unroll
    for (int j=0;j<4;j++) xs[j][s] = x[(n0+j)*SS + 192 + s];
    __syncthreads();
    float mz[4]={0,0,0,0}, mr[4]={0,0,0,0}, mh[4]={0,0,0,0};
    for (int sp=0; sp<5; sp++){
        const float* Pp = part + ((size_t)sp*NN + n0)*384;
        #pragma unroll
        for (int j=0;j<4;j++){
            mz[j] += Pp[j*384 + s];
            mr[j] += Pp[j*384 + 128 + s];
            mh[j] += Pp[j*384 + 256 + s];
        }
    }
    float dz[4]={0,0,0,0}, dr[4]={0,0,0,0};
    for (int k=0;k<SECD;k++){
        float wz_ = uz[k*SECD + s], wr_ = ur[k*SECD + s];
        #pragma unroll
        for (int j=0;j<4;j++){ float xv = xs[j][k]; dz[j] += xv*wz_; dr[j] += xv*wr_; }
    }
    float zz[4], rr[4];
    #pragma unroll
    for (int j=0;j<4;j++){
        zz[j] = sigmoidf_(mz[j] + dz[j] + bz[s]);
        rr[j] = sigmoidf_(mr[j] + dr[j] + br[s]);
        rx[j][s] = rr[j]*xs[j][s];
    }
    __syncthreads();
    float dh[4]={0,0,0,0};
    for (int k=0;k<SECD;k++){
        float wh_ = uh[k*SECD + s];
        #pragma unroll
        for (int j=0;j<4;j++) dh[j] += rx[j][k]*wh_;
    }
    #pragma unroll
    for (int j=0;j<4;j++){
        float h = tanhf(mh[j] + dh[j] + bh[s]);
        x[(n0+j)*SS + 192 + s] = (1.f - zz[j])*xs[j][s] + rr[j]*h;
    }
}

// ---------------- nb = relu(nh @ gb_w + gb_b), 8 notes/block -----------------------
__global__ void k_gb(const float* __restrict__ nh, const float* __restrict__ W,
                     const float* __restrict__ b, float* __restrict__ nb){
    int n0 = blockIdx.x*8, s = threadIdx.x;        // 320 threads
    __shared__ float xr[8][SS];
    #pragma unroll
    for (int j=0;j<8;j++) xr[j][s] = nh[(n0+j)*SS + s];
    __syncthreads();
    float acc[8]; float bv = b[s];
    #pragma unroll
    for (int j=0;j<8;j++) acc[j] = bv;
    for (int k=0;k<SS;k++){
        float w = W[k*SS + s];
        #pragma unroll
        for (int j=0;j<8;j++) acc[j] += xr[j][k]*w;
    }
    #pragma unroll
    for (int j=0;j<8;j++) nb[(n0+j)*SS + s] = fmaxf(acc[j], 0.f);
}

// ---------------- cat = [nh[:,192:320] | nh2[:,192:320]] ---------------------------
__global__ void k_build_cat(const float* __restrict__ nh, const float* __restrict__ nh2,
                            float* __restrict__ cat){
    int m = blockIdx.x, s = threadIdx.x;           // 256 threads
    cat[m*256 + s] = (s < 128) ? nh[m*SS + 192 + s] : nh2[m*SS + 64 + s];
}

// ---------------- attention sim: a=tanh(x@W+b); sim[m,h]=dot(a_head, c_head) -------
template<int D, int HD>
__global__ void k_att_sim(const float* __restrict__ x, const float* __restrict__ W,
                          const float* __restrict__ b, const float* __restrict__ c,
                          float* __restrict__ sim){
    int m0 = blockIdx.x*4, s = threadIdx.x;        // D threads
    __shared__ float xr[4][D];
    #pragma unroll
    for (int j=0;j<4;j++) xr[j][s] = x[(m0+j)*D + s];
    __syncthreads();
    float bias = b[s];
    float acc[4] = {bias,bias,bias,bias};
    for (int k=0;k<D;k++){
        float w = W[k*D + s];
        #pragma unroll
        for (int j=0;j<4;j++) acc[j] += xr[j][k]*w;
    }
    float cv = c[s];
    int h = s / HD;
    #pragma unroll
    for (int j=0;j<4;j++){
        float p = tanhf(acc[j])*cv;
        #pragma unroll
        for (int off=HD/2; off>0; off>>=1) p += __shfl_down(p, off);
        if ((s & (HD-1)) == 0) sim[(m0+j)*8 + h] = p;
    }
}

// ---------------- segment softmax (groups of 4 contiguous) + weighted sum ----------
template<int D, int HD>
__global__ void k_att_seg(const float* __restrict__ x, const float* __restrict__ sim,
                          float* __restrict__ out){
    int g = blockIdx.x, s = threadIdx.x;           // D threads
    __shared__ float wgt[4][8];
    if (s < 8){
        float v0 = sim[(g*4+0)*8+s], v1 = sim[(g*4+1)*8+s];
        float v2 = sim[(g*4+2)*8+s], v3 = sim[(g*4+3)*8+s];
        float mx = fmaxf(fmaxf(v0,v1), fmaxf(v2,v3));
        float e0 = expf(v0-mx), e1 = expf(v1-mx), e2 = expf(v2-mx), e3 = expf(v3-mx);
        float den = e0+e1+e2+e3;
        wgt[0][s]=e0/den; wgt[1][s]=e1/den; wgt[2][s]=e2/den; wgt[3][s]=e3/den;
    }
    __syncthreads();
    int h = s / HD;
    float o = 0.f;
    #pragma unroll
    for (int j=0;j<4;j++) o += x[(g*4+j)*D + s]*wgt[j][h];
    out[g*D + s] = o;
}

// ---------------- LSTM input pre-GEMM: g[t][gi] = b[gi] + wi[gi,:].x[t,:] ----------
template<int TIN, int G4>
__global__ void k_lstm_pre(const float* __restrict__ x,
        const float* __restrict__ wi_f, const float* __restrict__ b_f,
        const float* __restrict__ wi_b, const float* __restrict__ b_b,
        float* __restrict__ gf, float* __restrict__ gbo){
    int t0 = blockIdx.x*4, gi = threadIdx.x;       // G4 threads
    const float* wi = blockIdx.y ? wi_b : wi_f;
    const float* bb = blockIdx.y ? b_b  : b_f;
    float* go       = blockIdx.y ? gbo  : gf;
    __shared__ float xr[4][TIN];
    #pragma unroll
    for (int j=0;j<4;j++)
        for (int k=gi; k<TIN; k+=G4) xr[j][k] = x[(t0+j)*TIN + k];
    __syncthreads();
    float bv = bb[gi];
    float acc[4] = {bv,bv,bv,bv};
    const float* wrow = wi + (size_t)gi*TIN;
    for (int k=0;k<TIN;k++){
        float w = wrow[k];
        #pragma unroll
        for (int j=0;j<4;j++) acc[j] += xr[j][k]*w;
    }
    #pragma unroll
    for (int j=0;j<4;j++) go[(t0+j)*G4 + gi] = acc[j];
}

// ---------------- LSTM recurrence (round-1 rewrite) --------------------------------
// One block per direction, 4*H threads. Thread gi owns gate-row gi with its H
// recurrent weights in registers. h broadcast via uniform-address LDS float4
// reads (free broadcast). Two cheap barriers/step (4 waves for H=64).
template<int H, int T>
__global__ __launch_bounds__(4*H) void k_lstm_rec(
        const float* __restrict__ gin_f, const float* __restrict__ wh_f,
        const float* __restrict__ gin_b, const float* __restrict__ wh_b,
        float* __restrict__ hid /* [T][2H] */){
    int dir = blockIdx.x;
    const float* gin = dir ? gin_b : gin_f;
    const float* wh  = dir ? wh_b  : wh_f;
    int gi = threadIdx.x;                  // gate-row in [0, 4H)
    float wreg[H];
    #pragma unroll
    for (int k=0;k<H;k++) wreg[k] = wh[(size_t)gi*H + k];
    __shared__ __align__(16) float hs[H];
    __shared__ float gsum[4*H];
    float c = 0.f;
    if (gi < H) hs[gi] = 0.f;
    __syncthreads();
    int t0 = dir ? (T-1) : 0;
    float gcur = gin[t0*4*H + gi];
    for (int step=0; step<T; step++){
        int t = dir ? (T-1-step) : step;
        // prefetch next step's input-projection value
        float gnext = 0.f;
        if (step+1 < T){
            int tn = dir ? (T-2-step) : (step+1);
            gnext = gin[tn*4*H + gi];
        }
        float a = gcur;
        #pragma unroll
        for (int k=0;k<H;k+=4){
            float4 hv = *(const float4*)(hs + k);   // uniform addr -> broadcast
            a += wreg[k]*hv.x + wreg[k+1]*hv.y + wreg[k+2]*hv.z + wreg[k+3]*hv.w;
        }
        gsum[gi] = a;
        __syncthreads();
        if (gi < H){
            float ig = gsum[gi], fg = gsum[H+gi], gg = gsum[2*H+gi], og = gsum[3*H+gi];
            c = sigmoidf_(fg)*c + sigmoidf_(ig)*tanhf(gg);
            float hn = sigmoidf_(og)*tanhf(c);
            hs[gi] = hn;
            hid[t*2*H + dir*H + gi] = hn;
        }
        __syncthreads();
        gcur = gnext;
    }
}

// ---------------- rebuild notes_hidden = [beat_span | meas_span | nh_sec] ----------
__global__ void k_spans(float* __restrict__ nhid, const float* __restrict__ bh,
                        const float* __restrict__ mh, const float* __restrict__ nh,
                        const int* __restrict__ bn, const int* __restrict__ mn){
    int n = blockIdx.x, s = threadIdx.x;           // 320 threads
    float v;
    if (s < 128)      v = bh[bn[n]*128 + s];
    else if (s < 192) v = mh[mn[n]*64 + (s-128)];
    else              v = nh[n*SS + s];
    nhid[n*SS + s] = v;
}

// ---------------- final output = [notes_hidden(320) | nh2_sec(128)] ----------------
__global__ void k_final(const float* __restrict__ nhid, const float* __restrict__ nh2,
                        float* __restrict__ out){
    int n = blockIdx.x, s = threadIdx.x;           // 448 threads
    out[n*448 + s] = (s < 320) ? nhid[n*SS + s] : nh2[n*SS + 192 + (s-320)];
}

// ===========================================================================
extern "C" void kernel_launch(void* const* d_in, const int* in_sizes, int n_in,
                              void* d_out, int out_size, void* d_ws, size_t ws_size,
                              hipStream_t stream) {
    // --- inputs (setup_inputs dict order) ---
    const float* nodes    = (const float*)d_in[0];
    const float* adj      = (const float*)d_in[1];
    const int*   bn       = (const int*)  d_in[2];
    const int*   mn       = (const int*)  d_in[3];
    const float* fc_w     = (const float*)d_in[6];
    const float* fc_b     = (const float*)d_in[7];
    const float* g_wz[2]  = {(const float*)d_in[8],  (const float*)d_in[17]};
    const float* g_wr[2]  = {(const float*)d_in[9],  (const float*)d_in[18]};
    const float* g_wh[2]  = {(const float*)d_in[10], (const float*)d_in[19]};
    const float* g_uz[2]  = {(const float*)d_in[11], (const float*)d_in[20]};
    const float* g_ur[2]  = {(const float*)d_in[12], (const float*)d_in[21]};
    const float* g_uh[2]  = {(const float*)d_in[13], (const float*)d_in[22]};
    const float* g_bz[2]  = {(const float*)d_in[14], (const float*)d_in[23]};
    const float* g_br[2]  = {(const float*)d_in[15], (const float*)d_in[24]};
    const float* g_bh[2]  = {(const float*)d_in[16], (const float*)d_in[25]};
    const float* gb_w     = (const float*)d_in[26];
    const float* gb_b     = (const float*)d_in[27];
    const float* batt_w   = (const float*)d_in[28];
    const float* batt_b   = (const float*)d_in[29];
    const float* batt_c   = (const float*)d_in[30];
    const float* matt_w   = (const float*)d_in[31];
    const float* matt_b   = (const float*)d_in[32];
    const float* matt_c   = (const float*)d_in[33];
    const float* bwi_f    = (const float*)d_in[34];
    const float* bwh_f    = (const float*)d_in[35];
    const float* bb_f     = (const float*)d_in[36];
    const float* bwi_b    = (const float*)d_in[37];
    const float* bwh_b    = (const float*)d_in[38];
    const float* bb_b     = (const float*)d_in[39];
    const float* mwi_f    = (const float*)d_in[40];
    const float* mwh_f    = (const float*)d_in[41];
    const float* mb_f     = (const float*)d_in[42];
    const float* mwi_b    = (const float*)d_in[43];
    const float* mwh_b    = (const float*)d_in[44];
    const float* mb_b     = (const float*)d_in[45];
    float* out = (float*)d_out;

    // --- workspace layout (floats; total ~31 MB) ---
    float* W_   = (float*)d_ws;
    float* nhid = W_;                       // 1024*320
    float* nh   = nhid + 327680;            // 1024*320
    float* nh2  = nh   + 327680;            // 1024*320
    float* nb   = nh2  + 327680;            // 1024*320
    float* act  = nb   + 327680;            // 10*1024*320
    float* part = act  + 3276800;           // 5*1024*384
    float* cat  = part + 1966080;           // 1024*256
    float* sim  = cat  + 262144;            // 1024*8
    float* beat_nodes = sim + 8192;         // 256*256
    float* bgf  = beat_nodes + 65536;       // 256*256
    float* bgb  = bgf  + 65536;             // 256*256
    float* beat_hidden = bgb + 65536;       // 256*128
    float* msim = beat_hidden + 32768;      // 256*8
    float* meas_nodes = msim + 2048;        // 64*128
    float* mgf  = meas_nodes + 8192;        // 64*128
    float* mgb  = mgf  + 8192;              // 64*128
    float* meas_hidden = mgb + 8192;        // 64*64
    int*   cnt  = (int*)(meas_hidden + 4096);  // 10*1024
    int*   idx  = cnt + 10240;                  // 10*1024*64

    // --- adjacency -> column lists (once per launch; ws re-poisoned each call) ---
    hipMemsetAsync(cnt, 0, EE*NN*sizeof(int), stream);
    k_csr_build<<<EE*NN, 256, 0, stream>>>(adj, cnt, idx);

    // --- initial notes_hidden ---
    k_note_fc<<<NN, 128, 0, stream>>>(nodes, fc_w, fc_b, nhid);

    for (int si = 0; si < 2; ++si){
        // ---- nh = gated_graph(notes_hidden, g1) ----
        hipMemcpyAsync(nh, nhid, (size_t)NN*SS*sizeof(float), hipMemcpyDeviceToDevice, stream);
        for (int it = 0; it < 2; ++it){
            k_gather_act<<<EE*NN, SS, 0, stream>>>(nh, cnt, idx, act);
            k_gate_gemm<<<dim3(16,3,5), 256, 0, stream>>>(act, g_wz[0], g_wr[0], g_wh[0], part);
            k_gru<<<NN/4, 128, 0, stream>>>(nh, part, g_uz[0], g_ur[0], g_uh[0],
                                            g_bz[0], g_br[0], g_bh[0]);
        }
        // ---- nb = relu(nh @ gb_w + gb_b) ----
        k_gb<<<NN/8, SS, 0, stream>>>(nh, gb_w, gb_b, nb);
        // ---- nh2 = gated_graph(nb, g2) ----
        hipMemcpyAsync(nh2, nb, (size_t)NN*SS*sizeof(float), hipMemcpyDeviceToDevice, stream);
        for (int it = 0; it < 2; ++it){
            k_gather_act<<<EE*NN, SS, 0, stream>>>(nh2, cnt, idx, act);
            k_gate_gemm<<<dim3(16,3,5), 256, 0, stream>>>(act, g_wz[1], g_wr[1], g_wh[1], part);
            k_gru<<<NN/4, 128, 0, stream>>>(nh2, part, g_uz[1], g_ur[1], g_uh[1],
                                            g_bz[1], g_br[1], g_bh[1]);
        }
        // ---- beat attention over cat = [nh_sec | nh2_sec] ----
        k_build_cat<<<NN, 256, 0, stream>>>(nh, nh2, cat);
        k_att_sim<256,32><<<NN/4, 256, 0, stream>>>(cat, batt_w, batt_b, batt_c, sim);
        k_att_seg<256,32><<<NB, 256, 0, stream>>>(cat, sim, beat_nodes);
        // ---- beat BiLSTM (hidden 64, T=256) ----
        k_lstm_pre<256,256><<<dim3(NB/4,2), 256, 0, stream>>>(beat_nodes, bwi_f, bb_f,
                                                              bwi_b, bb_b, bgf, bgb);
        k_lstm_rec<64,256><<<2, 256, 0, stream>>>(bgf, bwh_f, bgb, bwh_b, beat_hidden);
        // ---- measure attention over beat_hidden ----
        k_att_sim<128,16><<<NB/4, 128, 0, stream>>>(beat_hidden, matt_w, matt_b, matt_c, msim);
        k_att_seg<128,16><<<NM, 128, 0, stream>>>(beat_hidden, msim, meas_nodes);
        // ---- measure BiLSTM (hidden 32, T=64) ----
        k_lstm_pre<128,128><<<dim3(NM/4,2), 128, 0, stream>>>(meas_nodes, mwi_f, mb_f,
                                                              mwi_b, mb_b, mgf, mgb);
        k_lstm_rec<32,64><<<2, 128, 0, stream>>>(mgf, mwh_f, mgb, mwh_b, meas_hidden);
        // ---- notes_hidden = [beat_span | meas_span | nh_sec] ----
        k_spans<<<NN, SS, 0, stream>>>(nhid, beat_hidden, meas_hidden, nh, bn, mn);
    }
    // ---- final = [notes_hidden | nh2_sec] ----
    k_final<<<NN, 448, 0, stream>>>(nhid, nh2, out);
}

// Round 3
// 1659.219 us; speedup vs baseline: 1.0903x; 1.0888x over previous
//
#include <hip/hip_runtime.h>
#include <math.h>

// ---------------------------------------------------------------------------
// IsgnBeatMeasEncoder — round 2: LSTM rec with explicit float4 reg weights
// (round-1 failure: float wreg[H] stayed in scratch — SROA can't promote
//  loop-indexed arrays; VGPR_Count=48 proved it. Now w0..w15 scalar float4s.)
// ---------------------------------------------------------------------------

#define NN    1024
#define EE    10
#define INDIM 78
#define SS    320
#define SECD  128
#define NB    256
#define NM    64
#define CAP   64     // max nonzeros per adjacency column (mean ~10.2)

__device__ __forceinline__ float fsig(float x){
    return __builtin_amdgcn_rcpf(1.f + __expf(-x));
}
__device__ __forceinline__ float ftanh(float x){
    // tanh(x) = 1 - 2/(exp(2x)+1); exp overflow -> inf -> rcp -> 0 -> 1 (correct)
    return 1.f - 2.f*__builtin_amdgcn_rcpf(1.f + __expf(2.f*x));
}

// ---------------- note_fc: x0 = tanh(nodes @ W + b); notes_hidden = [0(192) | x0] ----
__global__ void k_note_fc(const float* __restrict__ nodes, const float* __restrict__ W,
                          const float* __restrict__ b, float* __restrict__ nhid){
    int n = blockIdx.x, s = threadIdx.x;           // 128 threads
    __shared__ float xrow[INDIM];
    if (s < INDIM) xrow[s] = nodes[n*INDIM + s];
    __syncthreads();
    float acc = b[s];
    for (int k = 0; k < INDIM; ++k) acc += xrow[k]*W[k*128 + s];
    nhid[n*SS + 192 + s] = ftanh(acc);
    nhid[n*SS + s] = 0.f;
    if (s < 64) nhid[n*SS + 128 + s] = 0.f;
}

// ---------------- CSR build: for each (e, column n) list of source rows m ----------
__global__ void k_csr_build(const float* __restrict__ adj, int* __restrict__ cnt,
                            int* __restrict__ idx){
    int em = blockIdx.x;                   // e*NN + m  (row of adj[e])
    int e = em / NN, m = em % NN;
    const float* row = adj + (size_t)em * NN;
    for (int n = threadIdx.x; n < NN; n += blockDim.x){
        if (row[n] != 0.f){
            int p = atomicAdd(&cnt[e*NN + n], 1);
            if (p < CAP) idx[((size_t)e*NN + n)*CAP + p] = m;
        }
    }
}

// ---------------- act[e,n,f] = sum over column list of x[m,f] ----------------------
__global__ void k_gather_act(const float* __restrict__ x, const int* __restrict__ cnt,
                             const int* __restrict__ idx, float* __restrict__ act){
    int en = blockIdx.x, f = threadIdx.x;  // 320 threads
    int c = cnt[en]; if (c > CAP) c = CAP;
    const int* lst = idx + (size_t)en*CAP;
    float acc = 0.f;
    for (int j = 0; j < c; ++j) acc += x[lst[j]*SS + f];
    act[(size_t)en*SS + f] = acc;
}

// ---------------- gate GEMM: part[z][n][g*128+s] = sum_{e in pair z, f} act*w -------
__global__ __launch_bounds__(256) void k_gate_gemm(const float* __restrict__ act,
        const float* __restrict__ wz, const float* __restrict__ wr,
        const float* __restrict__ wh, float* __restrict__ part){
    __shared__ float A[32*76];     // [kk][row], pad 76
    __shared__ float B[32*132];    // [kk][col], pad 132
    int nt = blockIdx.x, g = blockIdx.y, z = blockIdx.z;
    const float* W = (g==0) ? wz : ((g==1) ? wr : wh);
    int tid = threadIdx.x;
    int tx = tid & 31;             // cols tx*4 .. +3
    int ty = tid >> 5;             // rows ty*8 .. +7
    float acc[8][4];
    #pragma unroll
    for (int i=0;i<8;i++){ acc[i][0]=0.f; acc[i][1]=0.f; acc[i][2]=0.f; acc[i][3]=0.f; }
    for (int eh = 0; eh < 2; ++eh){
        int e = z*2 + eh;
        const float* Ae = act + (size_t)e*NN*SS + (size_t)nt*64*SS;
        const float* We = W   + (size_t)e*SS*SECD;
        for (int kc = 0; kc < SS; kc += 32){
            #pragma unroll
            for (int i=0;i<2;i++){                 // A: 64 rows x 32 k
                int lin4 = tid + i*256;            // 512 float4
                int r  = lin4 >> 3;
                int k4 = (lin4 & 7) << 2;
                float4 v = *(const float4*)(Ae + r*SS + kc + k4);
                A[(k4+0)*76 + r] = v.x; A[(k4+1)*76 + r] = v.y;
                A[(k4+2)*76 + r] = v.z; A[(k4+3)*76 + r] = v.w;
            }
            #pragma unroll
            for (int i=0;i<4;i++){                 // B: 32 k x 128 cols
                int lin4 = tid + i*256;            // 1024 float4
                int kk = lin4 >> 5;
                int c4 = (lin4 & 31) << 2;
                *((float4*)(B + kk*132 + c4)) = *(const float4*)(We + (kc+kk)*SECD + c4);
            }
            __syncthreads();
            #pragma unroll 8
            for (int k=0;k<32;k++){
                float4 a0 = *(const float4*)(A + k*76 + ty*8);
                float4 a1 = *(const float4*)(A + k*76 + ty*8 + 4);
                float4 b0 = *(const float4*)(B + k*132 + tx*4);
                float av[8] = {a0.x,a0.y,a0.z,a0.w,a1.x,a1.y,a1.z,a1.w};
                float bv[4] = {b0.x,b0.y,b0.z,b0.w};
                #pragma unroll
                for (int i=0;i<8;i++)
                    #pragma unroll
                    for (int j=0;j<4;j++) acc[i][j] += av[i]*bv[j];
            }
            __syncthreads();
        }
    }
    float* P = part + ((size_t)z*NN + (size_t)nt*64)*384 + g*SECD;
    #pragma unroll
    for (int i=0;i<8;i++){
        int r = ty*8 + i;
        *(float4*)(P + (size_t)r*384 + tx*4) =
            make_float4(acc[i][0],acc[i][1],acc[i][2],acc[i][3]);
    }
}

// ---------------- GRU update (in place on x's last 128 cols), 4 notes/block --------
__global__ void k_gru(float* __restrict__ x, const float* __restrict__ part,
        const float* __restrict__ uz, const float* __restrict__ ur, const float* __restrict__ uh,
        const float* __restrict__ bz, const float* __restrict__ br, const float* __restrict__ bh){
    int n0 = blockIdx.x*4, s = threadIdx.x;        // 128 threads
    __shared__ float xs[4][SECD], rx[4][SECD];
    #pragma unroll
    for (int j=0;j<4;j++) xs[j][s] = x[(n0+j)*SS + 192 + s];
    __syncthreads();
    float mz[4]={0,0,0,0}, mr[4]={0,0,0,0}, mh[4]={0,0,0,0};
    for (int sp=0; sp<5; sp++){
        const float* Pp = part + ((size_t)sp*NN + n0)*384;
        #pragma unroll
        for (int j=0;j<4;j++){
            mz[j] += Pp[j*384 + s];
            mr[j] += Pp[j*384 + 128 + s];
            mh[j] += Pp[j*384 + 256 + s];
        }
    }
    float dz[4]={0,0,0,0}, dr[4]={0,0,0,0};
    for (int k=0;k<SECD;k++){
        float wz_ = uz[k*SECD + s], wr_ = ur[k*SECD + s];
        #pragma unroll
        for (int j=0;j<4;j++){ float xv = xs[j][k]; dz[j] += xv*wz_; dr[j] += xv*wr_; }
    }
    float zz[4], rr[4];
    #pragma unroll
    for (int j=0;j<4;j++){
        zz[j] = fsig(mz[j] + dz[j] + bz[s]);
        rr[j] = fsig(mr[j] + dr[j] + br[s]);
        rx[j][s] = rr[j]*xs[j][s];
    }
    __syncthreads();
    float dh[4]={0,0,0,0};
    for (int k=0;k<SECD;k++){
        float wh_ = uh[k*SECD + s];
        #pragma unroll
        for (int j=0;j<4;j++) dh[j] += rx[j][k]*wh_;
    }
    #pragma unroll
    for (int j=0;j<4;j++){
        float h = ftanh(mh[j] + dh[j] + bh[s]);
        x[(n0+j)*SS + 192 + s] = (1.f - zz[j])*xs[j][s] + rr[j]*h;
    }
}

// ---------------- nb = relu(nh @ gb_w + gb_b), 8 notes/block -----------------------
__global__ void k_gb(const float* __restrict__ nh, const float* __restrict__ W,
                     const float* __restrict__ b, float* __restrict__ nb){
    int n0 = blockIdx.x*8, s = threadIdx.x;        // 320 threads
    __shared__ float xr[8][SS];
    #pragma unroll
    for (int j=0;j<8;j++) xr[j][s] = nh[(n0+j)*SS + s];
    __syncthreads();
    float acc[8]; float bv = b[s];
    #pragma unroll
    for (int j=0;j<8;j++) acc[j] = bv;
    for (int k=0;k<SS;k++){
        float w = W[k*SS + s];
        #pragma unroll
        for (int j=0;j<8;j++) acc[j] += xr[j][k]*w;
    }
    #pragma unroll
    for (int j=0;j<8;j++) nb[(n0+j)*SS + s] = fmaxf(acc[j], 0.f);
}

// ---------------- cat = [nh[:,192:320] | nh2[:,192:320]] ---------------------------
__global__ void k_build_cat(const float* __restrict__ nh, const float* __restrict__ nh2,
                            float* __restrict__ cat){
    int m = blockIdx.x, s = threadIdx.x;           // 256 threads
    cat[m*256 + s] = (s < 128) ? nh[m*SS + 192 + s] : nh2[m*SS + 64 + s];
}

// ---------------- attention sim: a=tanh(x@W+b); sim[m,h]=dot(a_head, c_head) -------
template<int D, int HD>
__global__ void k_att_sim(const float* __restrict__ x, const float* __restrict__ W,
                          const float* __restrict__ b, const float* __restrict__ c,
                          float* __restrict__ sim){
    int m0 = blockIdx.x*4, s = threadIdx.x;        // D threads
    __shared__ float xr[4][D];
    #pragma unroll
    for (int j=0;j<4;j++) xr[j][s] = x[(m0+j)*D + s];
    __syncthreads();
    float bias = b[s];
    float acc[4] = {bias,bias,bias,bias};
    for (int k=0;k<D;k++){
        float w = W[k*D + s];
        #pragma unroll
        for (int j=0;j<4;j++) acc[j] += xr[j][k]*w;
    }
    float cv = c[s];
    int h = s / HD;
    #pragma unroll
    for (int j=0;j<4;j++){
        float p = ftanh(acc[j])*cv;
        #pragma unroll
        for (int off=HD/2; off>0; off>>=1) p += __shfl_down(p, off);
        if ((s & (HD-1)) == 0) sim[(m0+j)*8 + h] = p;
    }
}

// ---------------- segment softmax (groups of 4 contiguous) + weighted sum ----------
template<int D, int HD>
__global__ void k_att_seg(const float* __restrict__ x, const float* __restrict__ sim,
                          float* __restrict__ out){
    int g = blockIdx.x, s = threadIdx.x;           // D threads
    __shared__ float wgt[4][8];
    if (s < 8){
        float v0 = sim[(g*4+0)*8+s], v1 = sim[(g*4+1)*8+s];
        float v2 = sim[(g*4+2)*8+s], v3 = sim[(g*4+3)*8+s];
        float mx = fmaxf(fmaxf(v0,v1), fmaxf(v2,v3));
        float e0 = __expf(v0-mx), e1 = __expf(v1-mx), e2 = __expf(v2-mx), e3 = __expf(v3-mx);
        float den = e0+e1+e2+e3;
        wgt[0][s]=e0/den; wgt[1][s]=e1/den; wgt[2][s]=e2/den; wgt[3][s]=e3/den;
    }
    __syncthreads();
    int h = s / HD;
    float o = 0.f;
    #pragma unroll
    for (int j=0;j<4;j++) o += x[(g*4+j)*D + s]*wgt[j][h];
    out[g*D + s] = o;
}

// ---------------- LSTM input pre-GEMM: g[t][gi] = b[gi] + wi[gi,:].x[t,:] ----------
template<int TIN, int G4>
__global__ void k_lstm_pre(const float* __restrict__ x,
        const float* __restrict__ wi_f, const float* __restrict__ b_f,
        const float* __restrict__ wi_b, const float* __restrict__ b_b,
        float* __restrict__ gf, float* __restrict__ gbo){
    int t0 = blockIdx.x*4, gi = threadIdx.x;       // G4 threads
    const float* wi = blockIdx.y ? wi_b : wi_f;
    const float* bb = blockIdx.y ? b_b  : b_f;
    float* go       = blockIdx.y ? gbo  : gf;
    __shared__ float xr[4][TIN];
    #pragma unroll
    for (int j=0;j<4;j++)
        for (int k=gi; k<TIN; k+=G4) xr[j][k] = x[(t0+j)*TIN + k];
    __syncthreads();
    float bv = bb[gi];
    float acc[4] = {bv,bv,bv,bv};
    const float* wrow = wi + (size_t)gi*TIN;
    for (int k=0;k<TIN;k++){
        float w = wrow[k];
        #pragma unroll
        for (int j=0;j<4;j++) acc[j] += xr[j][k]*w;
    }
    #pragma unroll
    for (int j=0;j<4;j++) go[(t0+j)*G4 + gi] = acc[j];
}

// ---------------- LSTM recurrence, H=64 T=256: explicit float4 reg weights ---------
#define DOT4(A,W,HV) { A += W.x*HV.x; A += W.y*HV.y; A += W.z*HV.z; A += W.w*HV.w; }
__global__ __launch_bounds__(256) void k_lstm_rec64(
        const float* __restrict__ gin_f, const float* __restrict__ wh_f,
        const float* __restrict__ gin_b, const float* __restrict__ wh_b,
        float* __restrict__ hid /* [T][128] */){
    const int H = 64, T = 256;
    int dir = blockIdx.x;
    const float* gin = dir ? gin_b : gin_f;
    const float* wh  = dir ? wh_b  : wh_f;
    int gi = threadIdx.x;                  // gate-row in [0, 256)
    const float4* wr = (const float4*)(wh + (size_t)gi*H);
    float4 w0=wr[0], w1=wr[1], w2=wr[2],  w3=wr[3],  w4=wr[4],  w5=wr[5],  w6=wr[6],  w7=wr[7];
    float4 w8=wr[8], w9=wr[9], w10=wr[10],w11=wr[11],w12=wr[12],w13=wr[13],w14=wr[14],w15=wr[15];
    __shared__ __align__(16) float hs[H];
    __shared__ float gsum[4*H];
    float c = 0.f;
    if (gi < H) hs[gi] = 0.f;
    __syncthreads();
    float gcur = gin[(dir ? (T-1) : 0)*4*H + gi];
    for (int step=0; step<T; step++){
        int t = dir ? (T-1-step) : step;
        float gnext = 0.f;
        if (step+1 < T) gnext = gin[(dir ? (T-2-step) : (step+1))*4*H + gi];
        const float4* hv = (const float4*)hs;      // uniform addr -> LDS broadcast
        float4 h0=hv[0], h1=hv[1], h2=hv[2],  h3=hv[3],  h4=hv[4],  h5=hv[5],  h6=hv[6],  h7=hv[7];
        float4 h8=hv[8], h9=hv[9], h10=hv[10],h11=hv[11],h12=hv[12],h13=hv[13],h14=hv[14],h15=hv[15];
        float a0 = gcur, a1 = 0.f, a2 = 0.f, a3 = 0.f;
        DOT4(a0,w0,h0)   DOT4(a1,w1,h1)   DOT4(a2,w2,h2)   DOT4(a3,w3,h3)
        DOT4(a0,w4,h4)   DOT4(a1,w5,h5)   DOT4(a2,w6,h6)   DOT4(a3,w7,h7)
        DOT4(a0,w8,h8)   DOT4(a1,w9,h9)   DOT4(a2,w10,h10) DOT4(a3,w11,h11)
        DOT4(a0,w12,h12) DOT4(a1,w13,h13) DOT4(a2,w14,h14) DOT4(a3,w15,h15)
        gsum[gi] = (a0+a1) + (a2+a3);
        __syncthreads();
        if (gi < H){
            float ig = gsum[gi], fg = gsum[H+gi], gg = gsum[2*H+gi], og = gsum[3*H+gi];
            c = fsig(fg)*c + fsig(ig)*ftanh(gg);
            float hn = fsig(og)*ftanh(c);
            hs[gi] = hn;
            hid[t*2*H + dir*H + gi] = hn;
        }
        __syncthreads();
        gcur = gnext;
    }
}

// ---------------- LSTM recurrence, H=32 T=64 ---------------------------------------
__global__ __launch_bounds__(128) void k_lstm_rec32(
        const float* __restrict__ gin_f, const float* __restrict__ wh_f,
        const float* __restrict__ gin_b, const float* __restrict__ wh_b,
        float* __restrict__ hid /* [T][64] */){
    const int H = 32, T = 64;
    int dir = blockIdx.x;
    const float* gin = dir ? gin_b : gin_f;
    const float* wh  = dir ? wh_b  : wh_f;
    int gi = threadIdx.x;                  // gate-row in [0, 128)
    const float4* wr = (const float4*)(wh + (size_t)gi*H);
    float4 w0=wr[0], w1=wr[1], w2=wr[2], w3=wr[3], w4=wr[4], w5=wr[5], w6=wr[6], w7=wr[7];
    __shared__ __align__(16) float hs[H];
    __shared__ float gsum[4*H];
    float c = 0.f;
    if (gi < H) hs[gi] = 0.f;
    __syncthreads();
    float gcur = gin[(dir ? (T-1) : 0)*4*H + gi];
    for (int step=0; step<T; step++){
        int t = dir ? (T-1-step) : step;
        float gnext = 0.f;
        if (step+1 < T) gnext = gin[(dir ? (T-2-step) : (step+1))*4*H + gi];
        const float4* hv = (const float4*)hs;
        float4 h0=hv[0], h1=hv[1], h2=hv[2], h3=hv[3], h4=hv[4], h5=hv[5], h6=hv[6], h7=hv[7];
        float a0 = gcur, a1 = 0.f, a2 = 0.f, a3 = 0.f;
        DOT4(a0,w0,h0) DOT4(a1,w1,h1) DOT4(a2,w2,h2) DOT4(a3,w3,h3)
        DOT4(a0,w4,h4) DOT4(a1,w5,h5) DOT4(a2,w6,h6) DOT4(a3,w7,h7)
        gsum[gi] = (a0+a1) + (a2+a3);
        __syncthreads();
        if (gi < H){
            float ig = gsum[gi], fg = gsum[H+gi], gg = gsum[2*H+gi], og = gsum[3*H+gi];
            c = fsig(fg)*c + fsig(ig)*ftanh(gg);
            float hn = fsig(og)*ftanh(c);
            hs[gi] = hn;
            hid[t*2*H + dir*H + gi] = hn;
        }
        __syncthreads();
        gcur = gnext;
    }
}

// ---------------- rebuild notes_hidden = [beat_span | meas_span | nh_sec] ----------
__global__ void k_spans(float* __restrict__ nhid, const float* __restrict__ bh,
                        const float* __restrict__ mh, const float* __restrict__ nh,
                        const int* __restrict__ bn, const int* __restrict__ mn){
    int n = blockIdx.x, s = threadIdx.x;           // 320 threads
    float v;
    if (s < 128)      v = bh[bn[n]*128 + s];
    else if (s < 192) v = mh[mn[n]*64 + (s-128)];
    else              v = nh[n*SS + s];
    nhid[n*SS + s] = v;
}

// ---------------- final output = [notes_hidden(320) | nh2_sec(128)] ----------------
__global__ void k_final(const float* __restrict__ nhid, const float* __restrict__ nh2,
                        float* __restrict__ out){
    int n = blockIdx.x, s = threadIdx.x;           // 448 threads
    out[n*448 + s] = (s < 320) ? nhid[n*SS + s] : nh2[n*SS + 192 + (s-320)];
}

// ===========================================================================
extern "C" void kernel_launch(void* const* d_in, const int* in_sizes, int n_in,
                              void* d_out, int out_size, void* d_ws, size_t ws_size,
                              hipStream_t stream) {
    const float* nodes    = (const float*)d_in[0];
    const float* adj      = (const float*)d_in[1];
    const int*   bn       = (const int*)  d_in[2];
    const int*   mn       = (const int*)  d_in[3];
    const float* fc_w     = (const float*)d_in[6];
    const float* fc_b     = (const float*)d_in[7];
    const float* g_wz[2]  = {(const float*)d_in[8],  (const float*)d_in[17]};
    const float* g_wr[2]  = {(const float*)d_in[9],  (const float*)d_in[18]};
    const float* g_wh[2]  = {(const float*)d_in[10], (const float*)d_in[19]};
    const float* g_uz[2]  = {(const float*)d_in[11], (const float*)d_in[20]};
    const float* g_ur[2]  = {(const float*)d_in[12], (const float*)d_in[21]};
    const float* g_uh[2]  = {(const float*)d_in[13], (const float*)d_in[22]};
    const float* g_bz[2]  = {(const float*)d_in[14], (const float*)d_in[23]};
    const float* g_br[2]  = {(const float*)d_in[15], (const float*)d_in[24]};
    const float* g_bh[2]  = {(const float*)d_in[16], (const float*)d_in[25]};
    const float* gb_w     = (const float*)d_in[26];
    const float* gb_b     = (const float*)d_in[27];
    const float* batt_w   = (const float*)d_in[28];
    const float* batt_b   = (const float*)d_in[29];
    const float* batt_c   = (const float*)d_in[30];
    const float* matt_w   = (const float*)d_in[31];
    const float* matt_b   = (const float*)d_in[32];
    const float* matt_c   = (const float*)d_in[33];
    const float* bwi_f    = (const float*)d_in[34];
    const float* bwh_f    = (const float*)d_in[35];
    const float* bb_f     = (const float*)d_in[36];
    const float* bwi_b    = (const float*)d_in[37];
    const float* bwh_b    = (const float*)d_in[38];
    const float* bb_b     = (const float*)d_in[39];
    const float* mwi_f    = (const float*)d_in[40];
    const float* mwh_f    = (const float*)d_in[41];
    const float* mb_f     = (const float*)d_in[42];
    const float* mwi_b    = (const float*)d_in[43];
    const float* mwh_b    = (const float*)d_in[44];
    const float* mb_b     = (const float*)d_in[45];
    float* out = (float*)d_out;

    // --- workspace layout (floats; total ~31 MB) ---
    float* W_   = (float*)d_ws;
    float* nhid = W_;                       // 1024*320
    float* nh   = nhid + 327680;            // 1024*320
    float* nh2  = nh   + 327680;            // 1024*320
    float* nb   = nh2  + 327680;            // 1024*320
    float* act  = nb   + 327680;            // 10*1024*320
    float* part = act  + 3276800;           // 5*1024*384
    float* cat  = part + 1966080;           // 1024*256
    float* sim  = cat  + 262144;            // 1024*8
    float* beat_nodes = sim + 8192;         // 256*256
    float* bgf  = beat_nodes + 65536;       // 256*256
    float* bgb  = bgf  + 65536;             // 256*256
    float* beat_hidden = bgb + 65536;       // 256*128
    float* msim = beat_hidden + 32768;      // 256*8
    float* meas_nodes = msim + 2048;        // 64*128
    float* mgf  = meas_nodes + 8192;        // 64*128
    float* mgb  = mgf  + 8192;              // 64*128
    float* meas_hidden = mgb + 8192;        // 64*64
    int*   cnt  = (int*)(meas_hidden + 4096);  // 10*1024
    int*   idx  = cnt + 10240;                  // 10*1024*64

    hipMemsetAsync(cnt, 0, EE*NN*sizeof(int), stream);
    k_csr_build<<<EE*NN, 256, 0, stream>>>(adj, cnt, idx);
    k_note_fc<<<NN, 128, 0, stream>>>(nodes, fc_w, fc_b, nhid);

    for (int si = 0; si < 2; ++si){
        hipMemcpyAsync(nh, nhid, (size_t)NN*SS*sizeof(float), hipMemcpyDeviceToDevice, stream);
        for (int it = 0; it < 2; ++it){
            k_gather_act<<<EE*NN, SS, 0, stream>>>(nh, cnt, idx, act);
            k_gate_gemm<<<dim3(16,3,5), 256, 0, stream>>>(act, g_wz[0], g_wr[0], g_wh[0], part);
            k_gru<<<NN/4, 128, 0, stream>>>(nh, part, g_uz[0], g_ur[0], g_uh[0],
                                            g_bz[0], g_br[0], g_bh[0]);
        }
        k_gb<<<NN/8, SS, 0, stream>>>(nh, gb_w, gb_b, nb);
        hipMemcpyAsync(nh2, nb, (size_t)NN*SS*sizeof(float), hipMemcpyDeviceToDevice, stream);
        for (int it = 0; it < 2; ++it){
            k_gather_act<<<EE*NN, SS, 0, stream>>>(nh2, cnt, idx, act);
            k_gate_gemm<<<dim3(16,3,5), 256, 0, stream>>>(act, g_wz[1], g_wr[1], g_wh[1], part);
            k_gru<<<NN/4, 128, 0, stream>>>(nh2, part, g_uz[1], g_ur[1], g_uh[1],
                                            g_bz[1], g_br[1], g_bh[1]);
        }
        k_build_cat<<<NN, 256, 0, stream>>>(nh, nh2, cat);
        k_att_sim<256,32><<<NN/4, 256, 0, stream>>>(cat, batt_w, batt_b, batt_c, sim);
        k_att_seg<256,32><<<NB, 256, 0, stream>>>(cat, sim, beat_nodes);
        k_lstm_pre<256,256><<<dim3(NB/4,2), 256, 0, stream>>>(beat_nodes, bwi_f, bb_f,
                                                              bwi_b, bb_b, bgf, bgb);
        k_lstm_rec64<<<2, 256, 0, stream>>>(bgf, bwh_f, bgb, bwh_b, beat_hidden);
        k_att_sim<128,16><<<NB/4, 128, 0, stream>>>(beat_hidden, matt_w, matt_b, matt_c, msim);
        k_att_seg<128,16><<<NM, 128, 0, stream>>>(beat_hidden, msim, meas_nodes);
        k_lstm_pre<128,128><<<dim3(NM/4,2), 128, 0, stream>>>(meas_nodes, mwi_f, mb_f,
                                                              mwi_b, mb_b, mgf, mgb);
        k_lstm_rec32<<<2, 128, 0, stream>>>(mgf, mwh_f, mgb, mwh_b, meas_hidden);
        k_spans<<<NN, SS, 0, stream>>>(nhid, beat_hidden, meas_hidden, nh, bn, mn);
    }
    k_final<<<NN, 448, 0, stream>>>(nhid, nh2, out);
}

// Round 4
// 1656.843 us; speedup vs baseline: 1.0919x; 1.0014x over previous
//
#include <hip/hip_runtime.h>
#include <math.h>

// ---------------------------------------------------------------------------
// IsgnBeatMeasEncoder — round 3: force LSTM weight residency with
// __launch_bounds__(T, 1). Round-2 failure: VGPR_Count=52 (< 64 weight regs)
// proved the allocator's occupancy heuristic sank the weight loads into the
// loop. Grid is 2 blocks — occupancy is irrelevant; give allocator ~512 VGPRs.
// ---------------------------------------------------------------------------

#define NN    1024
#define EE    10
#define INDIM 78
#define SS    320
#define SECD  128
#define NB    256
#define NM    64
#define CAP   64     // max nonzeros per adjacency column (mean ~10.2)

__device__ __forceinline__ float fsig(float x){
    return __builtin_amdgcn_rcpf(1.f + __expf(-x));
}
__device__ __forceinline__ float ftanh(float x){
    // tanh(x) = 1 - 2/(exp(2x)+1); exp overflow -> inf -> rcp -> 0 -> 1 (correct)
    return 1.f - 2.f*__builtin_amdgcn_rcpf(1.f + __expf(2.f*x));
}

// ---------------- note_fc: x0 = tanh(nodes @ W + b); notes_hidden = [0(192) | x0] ----
__global__ void k_note_fc(const float* __restrict__ nodes, const float* __restrict__ W,
                          const float* __restrict__ b, float* __restrict__ nhid){
    int n = blockIdx.x, s = threadIdx.x;           // 128 threads
    __shared__ float xrow[INDIM];
    if (s < INDIM) xrow[s] = nodes[n*INDIM + s];
    __syncthreads();
    float acc = b[s];
    for (int k = 0; k < INDIM; ++k) acc += xrow[k]*W[k*128 + s];
    nhid[n*SS + 192 + s] = ftanh(acc);
    nhid[n*SS + s] = 0.f;
    if (s < 64) nhid[n*SS + 128 + s] = 0.f;
}

// ---------------- CSR build: for each (e, column n) list of source rows m ----------
__global__ void k_csr_build(const float* __restrict__ adj, int* __restrict__ cnt,
                            int* __restrict__ idx){
    int em = blockIdx.x;                   // e*NN + m  (row of adj[e])
    int e = em / NN, m = em % NN;
    const float* row = adj + (size_t)em * NN;
    for (int n = threadIdx.x; n < NN; n += blockDim.x){
        if (row[n] != 0.f){
            int p = atomicAdd(&cnt[e*NN + n], 1);
            if (p < CAP) idx[((size_t)e*NN + n)*CAP + p] = m;
        }
    }
}

// ---------------- act[e,n,f] = sum over column list of x[m,f] ----------------------
__global__ void k_gather_act(const float* __restrict__ x, const int* __restrict__ cnt,
                             const int* __restrict__ idx, float* __restrict__ act){
    int en = blockIdx.x, f = threadIdx.x;  // 320 threads
    int c = cnt[en]; if (c > CAP) c = CAP;
    const int* lst = idx + (size_t)en*CAP;
    float acc = 0.f;
    for (int j = 0; j < c; ++j) acc += x[lst[j]*SS + f];
    act[(size_t)en*SS + f] = acc;
}

// ---------------- gate GEMM: part[z][n][g*128+s] = sum_{e in pair z, f} act*w -------
__global__ __launch_bounds__(256) void k_gate_gemm(const float* __restrict__ act,
        const float* __restrict__ wz, const float* __restrict__ wr,
        const float* __restrict__ wh, float* __restrict__ part){
    __shared__ float A[32*76];     // [kk][row], pad 76
    __shared__ float B[32*132];    // [kk][col], pad 132
    int nt = blockIdx.x, g = blockIdx.y, z = blockIdx.z;
    const float* W = (g==0) ? wz : ((g==1) ? wr : wh);
    int tid = threadIdx.x;
    int tx = tid & 31;             // cols tx*4 .. +3
    int ty = tid >> 5;             // rows ty*8 .. +7
    float acc[8][4];
    #pragma unroll
    for (int i=0;i<8;i++){ acc[i][0]=0.f; acc[i][1]=0.f; acc[i][2]=0.f; acc[i][3]=0.f; }
    for (int eh = 0; eh < 2; ++eh){
        int e = z*2 + eh;
        const float* Ae = act + (size_t)e*NN*SS + (size_t)nt*64*SS;
        const float* We = W   + (size_t)e*SS*SECD;
        for (int kc = 0; kc < SS; kc += 32){
            #pragma unroll
            for (int i=0;i<2;i++){                 // A: 64 rows x 32 k
                int lin4 = tid + i*256;            // 512 float4
                int r  = lin4 >> 3;
                int k4 = (lin4 & 7) << 2;
                float4 v = *(const float4*)(Ae + r*SS + kc + k4);
                A[(k4+0)*76 + r] = v.x; A[(k4+1)*76 + r] = v.y;
                A[(k4+2)*76 + r] = v.z; A[(k4+3)*76 + r] = v.w;
            }
            #pragma unroll
            for (int i=0;i<4;i++){                 // B: 32 k x 128 cols
                int lin4 = tid + i*256;            // 1024 float4
                int kk = lin4 >> 5;
                int c4 = (lin4 & 31) << 2;
                *((float4*)(B + kk*132 + c4)) = *(const float4*)(We + (kc+kk)*SECD + c4);
            }
            __syncthreads();
            #pragma unroll 8
            for (int k=0;k<32;k++){
                float4 a0 = *(const float4*)(A + k*76 + ty*8);
                float4 a1 = *(const float4*)(A + k*76 + ty*8 + 4);
                float4 b0 = *(const float4*)(B + k*132 + tx*4);
                float av[8] = {a0.x,a0.y,a0.z,a0.w,a1.x,a1.y,a1.z,a1.w};
                float bv[4] = {b0.x,b0.y,b0.z,b0.w};
                #pragma unroll
                for (int i=0;i<8;i++)
                    #pragma unroll
                    for (int j=0;j<4;j++) acc[i][j] += av[i]*bv[j];
            }
            __syncthreads();
        }
    }
    float* P = part + ((size_t)z*NN + (size_t)nt*64)*384 + g*SECD;
    #pragma unroll
    for (int i=0;i<8;i++){
        int r = ty*8 + i;
        *(float4*)(P + (size_t)r*384 + tx*4) =
            make_float4(acc[i][0],acc[i][1],acc[i][2],acc[i][3]);
    }
}

// ---------------- GRU update (in place on x's last 128 cols), 4 notes/block --------
__global__ void k_gru(float* __restrict__ x, const float* __restrict__ part,
        const float* __restrict__ uz, const float* __restrict__ ur, const float* __restrict__ uh,
        const float* __restrict__ bz, const float* __restrict__ br, const float* __restrict__ bh){
    int n0 = blockIdx.x*4, s = threadIdx.x;        // 128 threads
    __shared__ float xs[4][SECD], rx[4][SECD];
    #pragma unroll
    for (int j=0;j<4;j++) xs[j][s] = x[(n0+j)*SS + 192 + s];
    __syncthreads();
    float mz[4]={0,0,0,0}, mr[4]={0,0,0,0}, mh[4]={0,0,0,0};
    for (int sp=0; sp<5; sp++){
        const float* Pp = part + ((size_t)sp*NN + n0)*384;
        #pragma unroll
        for (int j=0;j<4;j++){
            mz[j] += Pp[j*384 + s];
            mr[j] += Pp[j*384 + 128 + s];
            mh[j] += Pp[j*384 + 256 + s];
        }
    }
    float dz[4]={0,0,0,0}, dr[4]={0,0,0,0};
    for (int k=0;k<SECD;k++){
        float wz_ = uz[k*SECD + s], wr_ = ur[k*SECD + s];
        #pragma unroll
        for (int j=0;j<4;j++){ float xv = xs[j][k]; dz[j] += xv*wz_; dr[j] += xv*wr_; }
    }
    float zz[4], rr[4];
    #pragma unroll
    for (int j=0;j<4;j++){
        zz[j] = fsig(mz[j] + dz[j] + bz[s]);
        rr[j] = fsig(mr[j] + dr[j] + br[s]);
        rx[j][s] = rr[j]*xs[j][s];
    }
    __syncthreads();
    float dh[4]={0,0,0,0};
    for (int k=0;k<SECD;k++){
        float wh_ = uh[k*SECD + s];
        #pragma unroll
        for (int j=0;j<4;j++) dh[j] += rx[j][k]*wh_;
    }
    #pragma unroll
    for (int j=0;j<4;j++){
        float h = ftanh(mh[j] + dh[j] + bh[s]);
        x[(n0+j)*SS + 192 + s] = (1.f - zz[j])*xs[j][s] + rr[j]*h;
    }
}

// ---------------- nb = relu(nh @ gb_w + gb_b), 8 notes/block -----------------------
__global__ void k_gb(const float* __restrict__ nh, const float* __restrict__ W,
                     const float* __restrict__ b, float* __restrict__ nb){
    int n0 = blockIdx.x*8, s = threadIdx.x;        // 320 threads
    __shared__ float xr[8][SS];
    #pragma unroll
    for (int j=0;j<8;j++) xr[j][s] = nh[(n0+j)*SS + s];
    __syncthreads();
    float acc[8]; float bv = b[s];
    #pragma unroll
    for (int j=0;j<8;j++) acc[j] = bv;
    for (int k=0;k<SS;k++){
        float w = W[k*SS + s];
        #pragma unroll
        for (int j=0;j<8;j++) acc[j] += xr[j][k]*w;
    }
    #pragma unroll
    for (int j=0;j<8;j++) nb[(n0+j)*SS + s] = fmaxf(acc[j], 0.f);
}

// ---------------- cat = [nh[:,192:320] | nh2[:,192:320]] ---------------------------
__global__ void k_build_cat(const float* __restrict__ nh, const float* __restrict__ nh2,
                            float* __restrict__ cat){
    int m = blockIdx.x, s = threadIdx.x;           // 256 threads
    cat[m*256 + s] = (s < 128) ? nh[m*SS + 192 + s] : nh2[m*SS + 64 + s];
}

// ---------------- attention sim: a=tanh(x@W+b); sim[m,h]=dot(a_head, c_head) -------
template<int D, int HD>
__global__ void k_att_sim(const float* __restrict__ x, const float* __restrict__ W,
                          const float* __restrict__ b, const float* __restrict__ c,
                          float* __restrict__ sim){
    int m0 = blockIdx.x*4, s = threadIdx.x;        // D threads
    __shared__ float xr[4][D];
    #pragma unroll
    for (int j=0;j<4;j++) xr[j][s] = x[(m0+j)*D + s];
    __syncthreads();
    float bias = b[s];
    float acc[4] = {bias,bias,bias,bias};
    for (int k=0;k<D;k++){
        float w = W[k*D + s];
        #pragma unroll
        for (int j=0;j<4;j++) acc[j] += xr[j][k]*w;
    }
    float cv = c[s];
    int h = s / HD;
    #pragma unroll
    for (int j=0;j<4;j++){
        float p = ftanh(acc[j])*cv;
        #pragma unroll
        for (int off=HD/2; off>0; off>>=1) p += __shfl_down(p, off);
        if ((s & (HD-1)) == 0) sim[(m0+j)*8 + h] = p;
    }
}

// ---------------- segment softmax (groups of 4 contiguous) + weighted sum ----------
template<int D, int HD>
__global__ void k_att_seg(const float* __restrict__ x, const float* __restrict__ sim,
                          float* __restrict__ out){
    int g = blockIdx.x, s = threadIdx.x;           // D threads
    __shared__ float wgt[4][8];
    if (s < 8){
        float v0 = sim[(g*4+0)*8+s], v1 = sim[(g*4+1)*8+s];
        float v2 = sim[(g*4+2)*8+s], v3 = sim[(g*4+3)*8+s];
        float mx = fmaxf(fmaxf(v0,v1), fmaxf(v2,v3));
        float e0 = __expf(v0-mx), e1 = __expf(v1-mx), e2 = __expf(v2-mx), e3 = __expf(v3-mx);
        float den = e0+e1+e2+e3;
        wgt[0][s]=e0/den; wgt[1][s]=e1/den; wgt[2][s]=e2/den; wgt[3][s]=e3/den;
    }
    __syncthreads();
    int h = s / HD;
    float o = 0.f;
    #pragma unroll
    for (int j=0;j<4;j++) o += x[(g*4+j)*D + s]*wgt[j][h];
    out[g*D + s] = o;
}

// ---------------- LSTM input pre-GEMM: g[t][gi] = b[gi] + wi[gi,:].x[t,:] ----------
template<int TIN, int G4>
__global__ void k_lstm_pre(const float* __restrict__ x,
        const float* __restrict__ wi_f, const float* __restrict__ b_f,
        const float* __restrict__ wi_b, const float* __restrict__ b_b,
        float* __restrict__ gf, float* __restrict__ gbo){
    int t0 = blockIdx.x*4, gi = threadIdx.x;       // G4 threads
    const float* wi = blockIdx.y ? wi_b : wi_f;
    const float* bb = blockIdx.y ? b_b  : b_f;
    float* go       = blockIdx.y ? gbo  : gf;
    __shared__ float xr[4][TIN];
    #pragma unroll
    for (int j=0;j<4;j++)
        for (int k=gi; k<TIN; k+=G4) xr[j][k] = x[(t0+j)*TIN + k];
    __syncthreads();
    float bv = bb[gi];
    float acc[4] = {bv,bv,bv,bv};
    const float* wrow = wi + (size_t)gi*TIN;
    for (int k=0;k<TIN;k++){
        float w = wrow[k];
        #pragma unroll
        for (int j=0;j<4;j++) acc[j] += xr[j][k]*w;
    }
    #pragma unroll
    for (int j=0;j<4;j++) go[(t0+j)*G4 + gi] = acc[j];
}

// ---------------- LSTM recurrence, H=64 T=256: reg weights, full VGPR budget -------
#define DOT4(A,W,HV) { A += W.x*HV.x; A += W.y*HV.y; A += W.z*HV.z; A += W.w*HV.w; }
__global__ __launch_bounds__(256, 1) void k_lstm_rec64(
        const float* __restrict__ gin_f, const float* __restrict__ wh_f,
        const float* __restrict__ gin_b, const float* __restrict__ wh_b,
        float* __restrict__ hid /* [T][128] */){
    const int H = 64, T = 256;
    int dir = blockIdx.x;
    const float* gin = dir ? gin_b : gin_f;
    const float* wh  = dir ? wh_b  : wh_f;
    int gi = threadIdx.x;                  // gate-row in [0, 256)
    const float4* wr = (const float4*)(wh + (size_t)gi*H);
    float4 w0=wr[0], w1=wr[1], w2=wr[2],  w3=wr[3],  w4=wr[4],  w5=wr[5],  w6=wr[6],  w7=wr[7];
    float4 w8=wr[8], w9=wr[9], w10=wr[10],w11=wr[11],w12=wr[12],w13=wr[13],w14=wr[14],w15=wr[15];
    __shared__ __align__(16) float hs[H];
    __shared__ float gsum[4*H];
    float c = 0.f;
    if (gi < H) hs[gi] = 0.f;
    __syncthreads();
    float gcur = gin[(dir ? (T-1) : 0)*4*H + gi];
    for (int step=0; step<T; step++){
        int t = dir ? (T-1-step) : step;
        float gnext = 0.f;
        if (step+1 < T) gnext = gin[(dir ? (T-2-step) : (step+1))*4*H + gi];
        const float4* hv = (const float4*)hs;      // uniform addr -> LDS broadcast
        float4 h0=hv[0], h1=hv[1], h2=hv[2],  h3=hv[3],  h4=hv[4],  h5=hv[5],  h6=hv[6],  h7=hv[7];
        float4 h8=hv[8], h9=hv[9], h10=hv[10],h11=hv[11],h12=hv[12],h13=hv[13],h14=hv[14],h15=hv[15];
        float a0 = gcur, a1 = 0.f, a2 = 0.f, a3 = 0.f;
        DOT4(a0,w0,h0)   DOT4(a1,w1,h1)   DOT4(a2,w2,h2)   DOT4(a3,w3,h3)
        DOT4(a0,w4,h4)   DOT4(a1,w5,h5)   DOT4(a2,w6,h6)   DOT4(a3,w7,h7)
        DOT4(a0,w8,h8)   DOT4(a1,w9,h9)   DOT4(a2,w10,h10) DOT4(a3,w11,h11)
        DOT4(a0,w12,h12) DOT4(a1,w13,h13) DOT4(a2,w14,h14) DOT4(a3,w15,h15)
        gsum[gi] = (a0+a1) + (a2+a3);
        __syncthreads();
        if (gi < H){
            float ig = gsum[gi], fg = gsum[H+gi], gg = gsum[2*H+gi], og = gsum[3*H+gi];
            c = fsig(fg)*c + fsig(ig)*ftanh(gg);
            float hn = fsig(og)*ftanh(c);
            hs[gi] = hn;
            hid[t*2*H + dir*H + gi] = hn;
        }
        __syncthreads();
        gcur = gnext;
    }
}

// ---------------- LSTM recurrence, H=32 T=64 ---------------------------------------
__global__ __launch_bounds__(128, 1) void k_lstm_rec32(
        const float* __restrict__ gin_f, const float* __restrict__ wh_f,
        const float* __restrict__ gin_b, const float* __restrict__ wh_b,
        float* __restrict__ hid /* [T][64] */){
    const int H = 32, T = 64;
    int dir = blockIdx.x;
    const float* gin = dir ? gin_b : gin_f;
    const float* wh  = dir ? wh_b  : wh_f;
    int gi = threadIdx.x;                  // gate-row in [0, 128)
    const float4* wr = (const float4*)(wh + (size_t)gi*H);
    float4 w0=wr[0], w1=wr[1], w2=wr[2], w3=wr[3], w4=wr[4], w5=wr[5], w6=wr[6], w7=wr[7];
    __shared__ __align__(16) float hs[H];
    __shared__ float gsum[4*H];
    float c = 0.f;
    if (gi < H) hs[gi] = 0.f;
    __syncthreads();
    float gcur = gin[(dir ? (T-1) : 0)*4*H + gi];
    for (int step=0; step<T; step++){
        int t = dir ? (T-1-step) : step;
        float gnext = 0.f;
        if (step+1 < T) gnext = gin[(dir ? (T-2-step) : (step+1))*4*H + gi];
        const float4* hv = (const float4*)hs;
        float4 h0=hv[0], h1=hv[1], h2=hv[2], h3=hv[3], h4=hv[4], h5=hv[5], h6=hv[6], h7=hv[7];
        float a0 = gcur, a1 = 0.f, a2 = 0.f, a3 = 0.f;
        DOT4(a0,w0,h0) DOT4(a1,w1,h1) DOT4(a2,w2,h2) DOT4(a3,w3,h3)
        DOT4(a0,w4,h4) DOT4(a1,w5,h5) DOT4(a2,w6,h6) DOT4(a3,w7,h7)
        gsum[gi] = (a0+a1) + (a2+a3);
        __syncthreads();
        if (gi < H){
            float ig = gsum[gi], fg = gsum[H+gi], gg = gsum[2*H+gi], og = gsum[3*H+gi];
            c = fsig(fg)*c + fsig(ig)*ftanh(gg);
            float hn = fsig(og)*ftanh(c);
            hs[gi] = hn;
            hid[t*2*H + dir*H + gi] = hn;
        }
        __syncthreads();
        gcur = gnext;
    }
}

// ---------------- rebuild notes_hidden = [beat_span | meas_span | nh_sec] ----------
__global__ void k_spans(float* __restrict__ nhid, const float* __restrict__ bh,
                        const float* __restrict__ mh, const float* __restrict__ nh,
                        const int* __restrict__ bn, const int* __restrict__ mn){
    int n = blockIdx.x, s = threadIdx.x;           // 320 threads
    float v;
    if (s < 128)      v = bh[bn[n]*128 + s];
    else if (s < 192) v = mh[mn[n]*64 + (s-128)];
    else              v = nh[n*SS + s];
    nhid[n*SS + s] = v;
}

// ---------------- final output = [notes_hidden(320) | nh2_sec(128)] ----------------
__global__ void k_final(const float* __restrict__ nhid, const float* __restrict__ nh2,
                        float* __restrict__ out){
    int n = blockIdx.x, s = threadIdx.x;           // 448 threads
    out[n*448 + s] = (s < 320) ? nhid[n*SS + s] : nh2[n*SS + 192 + (s-320)];
}

// ===========================================================================
extern "C" void kernel_launch(void* const* d_in, const int* in_sizes, int n_in,
                              void* d_out, int out_size, void* d_ws, size_t ws_size,
                              hipStream_t stream) {
    const float* nodes    = (const float*)d_in[0];
    const float* adj      = (const float*)d_in[1];
    const int*   bn       = (const int*)  d_in[2];
    const int*   mn       = (const int*)  d_in[3];
    const float* fc_w     = (const float*)d_in[6];
    const float* fc_b     = (const float*)d_in[7];
    const float* g_wz[2]  = {(const float*)d_in[8],  (const float*)d_in[17]};
    const float* g_wr[2]  = {(const float*)d_in[9],  (const float*)d_in[18]};
    const float* g_wh[2]  = {(const float*)d_in[10], (const float*)d_in[19]};
    const float* g_uz[2]  = {(const float*)d_in[11], (const float*)d_in[20]};
    const float* g_ur[2]  = {(const float*)d_in[12], (const float*)d_in[21]};
    const float* g_uh[2]  = {(const float*)d_in[13], (const float*)d_in[22]};
    const float* g_bz[2]  = {(const float*)d_in[14], (const float*)d_in[23]};
    const float* g_br[2]  = {(const float*)d_in[15], (const float*)d_in[24]};
    const float* g_bh[2]  = {(const float*)d_in[16], (const float*)d_in[25]};
    const float* gb_w     = (const float*)d_in[26];
    const float* gb_b     = (const float*)d_in[27];
    const float* batt_w   = (const float*)d_in[28];
    const float* batt_b   = (const float*)d_in[29];
    const float* batt_c   = (const float*)d_in[30];
    const float* matt_w   = (const float*)d_in[31];
    const float* matt_b   = (const float*)d_in[32];
    const float* matt_c   = (const float*)d_in[33];
    const float* bwi_f    = (const float*)d_in[34];
    const float* bwh_f    = (const float*)d_in[35];
    const float* bb_f     = (const float*)d_in[36];
    const float* bwi_b    = (const float*)d_in[37];
    const float* bwh_b    = (const float*)d_in[38];
    const float* bb_b     = (const float*)d_in[39];
    const float* mwi_f    = (const float*)d_in[40];
    const float* mwh_f    = (const float*)d_in[41];
    const float* mb_f     = (const float*)d_in[42];
    const float* mwi_b    = (const float*)d_in[43];
    const float* mwh_b    = (const float*)d_in[44];
    const float* mb_b     = (const float*)d_in[45];
    float* out = (float*)d_out;

    // --- workspace layout (floats; total ~31 MB) ---
    float* W_   = (float*)d_ws;
    float* nhid = W_;                       // 1024*320
    float* nh   = nhid + 327680;            // 1024*320
    float* nh2  = nh   + 327680;            // 1024*320
    float* nb   = nh2  + 327680;            // 1024*320
    float* act  = nb   + 327680;            // 10*1024*320
    float* part = act  + 3276800;           // 5*1024*384
    float* cat  = part + 1966080;           // 1024*256
    float* sim  = cat  + 262144;            // 1024*8
    float* beat_nodes = sim + 8192;         // 256*256
    float* bgf  = beat_nodes + 65536;       // 256*256
    float* bgb  = bgf  + 65536;             // 256*256
    float* beat_hidden = bgb + 65536;       // 256*128
    float* msim = beat_hidden + 32768;      // 256*8
    float* meas_nodes = msim + 2048;        // 64*128
    float* mgf  = meas_nodes + 8192;        // 64*128
    float* mgb  = mgf  + 8192;              // 64*128
    float* meas_hidden = mgb + 8192;        // 64*64
    int*   cnt  = (int*)(meas_hidden + 4096);  // 10*1024
    int*   idx  = cnt + 10240;                  // 10*1024*64

    hipMemsetAsync(cnt, 0, EE*NN*sizeof(int), stream);
    k_csr_build<<<EE*NN, 256, 0, stream>>>(adj, cnt, idx);
    k_note_fc<<<NN, 128, 0, stream>>>(nodes, fc_w, fc_b, nhid);

    for (int si = 0; si < 2; ++si){
        hipMemcpyAsync(nh, nhid, (size_t)NN*SS*sizeof(float), hipMemcpyDeviceToDevice, stream);
        for (int it = 0; it < 2; ++it){
            k_gather_act<<<EE*NN, SS, 0, stream>>>(nh, cnt, idx, act);
            k_gate_gemm<<<dim3(16,3,5), 256, 0, stream>>>(act, g_wz[0], g_wr[0], g_wh[0], part);
            k_gru<<<NN/4, 128, 0, stream>>>(nh, part, g_uz[0], g_ur[0], g_uh[0],
                                            g_bz[0], g_br[0], g_bh[0]);
        }
        k_gb<<<NN/8, SS, 0, stream>>>(nh, gb_w, gb_b, nb);
        hipMemcpyAsync(nh2, nb, (size_t)NN*SS*sizeof(float), hipMemcpyDeviceToDevice, stream);
        for (int it = 0; it < 2; ++it){
            k_gather_act<<<EE*NN, SS, 0, stream>>>(nh2, cnt, idx, act);
            k_gate_gemm<<<dim3(16,3,5), 256, 0, stream>>>(act, g_wz[1], g_wr[1], g_wh[1], part);
            k_gru<<<NN/4, 128, 0, stream>>>(nh2, part, g_uz[1], g_ur[1], g_uh[1],
                                            g_bz[1], g_br[1], g_bh[1]);
        }
        k_build_cat<<<NN, 256, 0, stream>>>(nh, nh2, cat);
        k_att_sim<256,32><<<NN/4, 256, 0, stream>>>(cat, batt_w, batt_b, batt_c, sim);
        k_att_seg<256,32><<<NB, 256, 0, stream>>>(cat, sim, beat_nodes);
        k_lstm_pre<256,256><<<dim3(NB/4,2), 256, 0, stream>>>(beat_nodes, bwi_f, bb_f,
                                                              bwi_b, bb_b, bgf, bgb);
        k_lstm_rec64<<<2, 256, 0, stream>>>(bgf, bwh_f, bgb, bwh_b, beat_hidden);
        k_att_sim<128,16><<<NB/4, 128, 0, stream>>>(beat_hidden, matt_w, matt_b, matt_c, msim);
        k_att_seg<128,16><<<NM, 128, 0, stream>>>(beat_hidden, msim, meas_nodes);
        k_lstm_pre<128,128><<<dim3(NM/4,2), 128, 0, stream>>>(meas_nodes, mwi_f, mb_f,
                                                              mwi_b, mb_b, mgf, mgb);
        k_lstm_rec32<<<2, 128, 0, stream>>>(mgf, mwh_f, mgb, mwh_b, meas_hidden);
        k_spans<<<NN, SS, 0, stream>>>(nhid, beat_hidden, meas_hidden, nh, bn, mn);
    }
    k_final<<<NN, 448, 0, stream>>>(nhid, nh2, out);
}

// Round 5
// 1617.767 us; speedup vs baseline: 1.1183x; 1.0242x over previous
//
#include <hip/hip_runtime.h>
#include <math.h>

// ---------------------------------------------------------------------------
// IsgnBeatMeasEncoder — round 4: kill weight-load rematerialization in the
// LSTM recurrences with amdgpu_waves_per_eu(1,1).
// Round-3 failure: __launch_bounds__(T,1) only sets MIN waves/EU; allocator
// still targeted high occupancy and REMATERIALIZED the 16 loop-invariant
// float4 weight loads inside the loop (VGPR_Count=52 unchanged) — re-reading
// 64KB of wh from L2 every step. waves_per_eu(1,1) caps the target too.
// ---------------------------------------------------------------------------

#define NN    1024
#define EE    10
#define INDIM 78
#define SS    320
#define SECD  128
#define NB    256
#define NM    64
#define CAP   64     // max nonzeros per adjacency column (mean ~10.2)

__device__ __forceinline__ float fsig(float x){
    return __builtin_amdgcn_rcpf(1.f + __expf(-x));
}
__device__ __forceinline__ float ftanh(float x){
    // tanh(x) = 1 - 2/(exp(2x)+1); exp overflow -> inf -> rcp -> 0 -> 1 (correct)
    return 1.f - 2.f*__builtin_amdgcn_rcpf(1.f + __expf(2.f*x));
}

// ---------------- note_fc: x0 = tanh(nodes @ W + b); notes_hidden = [0(192) | x0] ----
__global__ void k_note_fc(const float* __restrict__ nodes, const float* __restrict__ W,
                          const float* __restrict__ b, float* __restrict__ nhid){
    int n = blockIdx.x, s = threadIdx.x;           // 128 threads
    __shared__ float xrow[INDIM];
    if (s < INDIM) xrow[s] = nodes[n*INDIM + s];
    __syncthreads();
    float acc = b[s];
    for (int k = 0; k < INDIM; ++k) acc += xrow[k]*W[k*128 + s];
    nhid[n*SS + 192 + s] = ftanh(acc);
    nhid[n*SS + s] = 0.f;
    if (s < 64) nhid[n*SS + 128 + s] = 0.f;
}

// ---------------- CSR build: for each (e, column n) list of source rows m ----------
__global__ void k_csr_build(const float* __restrict__ adj, int* __restrict__ cnt,
                            int* __restrict__ idx){
    int em = blockIdx.x;                   // e*NN + m  (row of adj[e])
    int e = em / NN, m = em % NN;
    const float* row = adj + (size_t)em * NN;
    for (int n = threadIdx.x; n < NN; n += blockDim.x){
        if (row[n] != 0.f){
            int p = atomicAdd(&cnt[e*NN + n], 1);
            if (p < CAP) idx[((size_t)e*NN + n)*CAP + p] = m;
        }
    }
}

// ---------------- act[e,n,f] = sum over column list of x[m,f] ----------------------
__global__ void k_gather_act(const float* __restrict__ x, const int* __restrict__ cnt,
                             const int* __restrict__ idx, float* __restrict__ act){
    int en = blockIdx.x, f = threadIdx.x;  // 320 threads
    int c = cnt[en]; if (c > CAP) c = CAP;
    const int* lst = idx + (size_t)en*CAP;
    float acc = 0.f;
    for (int j = 0; j < c; ++j) acc += x[lst[j]*SS + f];
    act[(size_t)en*SS + f] = acc;
}

// ---------------- gate GEMM: part[z][n][g*128+s] = sum_{e in pair z, f} act*w -------
__global__ __launch_bounds__(256) void k_gate_gemm(const float* __restrict__ act,
        const float* __restrict__ wz, const float* __restrict__ wr,
        const float* __restrict__ wh, float* __restrict__ part){
    __shared__ float A[32*76];     // [kk][row], pad 76
    __shared__ float B[32*132];    // [kk][col], pad 132
    int nt = blockIdx.x, g = blockIdx.y, z = blockIdx.z;
    const float* W = (g==0) ? wz : ((g==1) ? wr : wh);
    int tid = threadIdx.x;
    int tx = tid & 31;             // cols tx*4 .. +3
    int ty = tid >> 5;             // rows ty*8 .. +7
    float acc[8][4];
    #pragma unroll
    for (int i=0;i<8;i++){ acc[i][0]=0.f; acc[i][1]=0.f; acc[i][2]=0.f; acc[i][3]=0.f; }
    for (int eh = 0; eh < 2; ++eh){
        int e = z*2 + eh;
        const float* Ae = act + (size_t)e*NN*SS + (size_t)nt*64*SS;
        const float* We = W   + (size_t)e*SS*SECD;
        for (int kc = 0; kc < SS; kc += 32){
            #pragma unroll
            for (int i=0;i<2;i++){                 // A: 64 rows x 32 k
                int lin4 = tid + i*256;            // 512 float4
                int r  = lin4 >> 3;
                int k4 = (lin4 & 7) << 2;
                float4 v = *(const float4*)(Ae + r*SS + kc + k4);
                A[(k4+0)*76 + r] = v.x; A[(k4+1)*76 + r] = v.y;
                A[(k4+2)*76 + r] = v.z; A[(k4+3)*76 + r] = v.w;
            }
            #pragma unroll
            for (int i=0;i<4;i++){                 // B: 32 k x 128 cols
                int lin4 = tid + i*256;            // 1024 float4
                int kk = lin4 >> 5;
                int c4 = (lin4 & 31) << 2;
                *((float4*)(B + kk*132 + c4)) = *(const float4*)(We + (kc+kk)*SECD + c4);
            }
            __syncthreads();
            #pragma unroll 8
            for (int k=0;k<32;k++){
                float4 a0 = *(const float4*)(A + k*76 + ty*8);
                float4 a1 = *(const float4*)(A + k*76 + ty*8 + 4);
                float4 b0 = *(const float4*)(B + k*132 + tx*4);
                float av[8] = {a0.x,a0.y,a0.z,a0.w,a1.x,a1.y,a1.z,a1.w};
                float bv[4] = {b0.x,b0.y,b0.z,b0.w};
                #pragma unroll
                for (int i=0;i<8;i++)
                    #pragma unroll
                    for (int j=0;j<4;j++) acc[i][j] += av[i]*bv[j];
            }
            __syncthreads();
        }
    }
    float* P = part + ((size_t)z*NN + (size_t)nt*64)*384 + g*SECD;
    #pragma unroll
    for (int i=0;i<8;i++){
        int r = ty*8 + i;
        *(float4*)(P + (size_t)r*384 + tx*4) =
            make_float4(acc[i][0],acc[i][1],acc[i][2],acc[i][3]);
    }
}

// ---------------- GRU update (in place on x's last 128 cols), 4 notes/block --------
__global__ void k_gru(float* __restrict__ x, const float* __restrict__ part,
        const float* __restrict__ uz, const float* __restrict__ ur, const float* __restrict__ uh,
        const float* __restrict__ bz, const float* __restrict__ br, const float* __restrict__ bh){
    int n0 = blockIdx.x*4, s = threadIdx.x;        // 128 threads
    __shared__ float xs[4][SECD], rx[4][SECD];
    #pragma unroll
    for (int j=0;j<4;j++) xs[j][s] = x[(n0+j)*SS + 192 + s];
    __syncthreads();
    float mz[4]={0,0,0,0}, mr[4]={0,0,0,0}, mh[4]={0,0,0,0};
    for (int sp=0; sp<5; sp++){
        const float* Pp = part + ((size_t)sp*NN + n0)*384;
        #pragma unroll
        for (int j=0;j<4;j++){
            mz[j] += Pp[j*384 + s];
            mr[j] += Pp[j*384 + 128 + s];
            mh[j] += Pp[j*384 + 256 + s];
        }
    }
    float dz[4]={0,0,0,0}, dr[4]={0,0,0,0};
    for (int k=0;k<SECD;k++){
        float wz_ = uz[k*SECD + s], wr_ = ur[k*SECD + s];
        #pragma unroll
        for (int j=0;j<4;j++){ float xv = xs[j][k]; dz[j] += xv*wz_; dr[j] += xv*wr_; }
    }
    float zz[4], rr[4];
    #pragma unroll
    for (int j=0;j<4;j++){
        zz[j] = fsig(mz[j] + dz[j] + bz[s]);
        rr[j] = fsig(mr[j] + dr[j] + br[s]);
        rx[j][s] = rr[j]*xs[j][s];
    }
    __syncthreads();
    float dh[4]={0,0,0,0};
    for (int k=0;k<SECD;k++){
        float wh_ = uh[k*SECD + s];
        #pragma unroll
        for (int j=0;j<4;j++) dh[j] += rx[j][k]*wh_;
    }
    #pragma unroll
    for (int j=0;j<4;j++){
        float h = ftanh(mh[j] + dh[j] + bh[s]);
        x[(n0+j)*SS + 192 + s] = (1.f - zz[j])*xs[j][s] + rr[j]*h;
    }
}

// ---------------- nb = relu(nh @ gb_w + gb_b), 8 notes/block -----------------------
__global__ void k_gb(const float* __restrict__ nh, const float* __restrict__ W,
                     const float* __restrict__ b, float* __restrict__ nb){
    int n0 = blockIdx.x*8, s = threadIdx.x;        // 320 threads
    __shared__ float xr[8][SS];
    #pragma unroll
    for (int j=0;j<8;j++) xr[j][s] = nh[(n0+j)*SS + s];
    __syncthreads();
    float acc[8]; float bv = b[s];
    #pragma unroll
    for (int j=0;j<8;j++) acc[j] = bv;
    for (int k=0;k<SS;k++){
        float w = W[k*SS + s];
        #pragma unroll
        for (int j=0;j<8;j++) acc[j] += xr[j][k]*w;
    }
    #pragma unroll
    for (int j=0;j<8;j++) nb[(n0+j)*SS + s] = fmaxf(acc[j], 0.f);
}

// ---------------- cat = [nh[:,192:320] | nh2[:,192:320]] ---------------------------
__global__ void k_build_cat(const float* __restrict__ nh, const float* __restrict__ nh2,
                            float* __restrict__ cat){
    int m = blockIdx.x, s = threadIdx.x;           // 256 threads
    cat[m*256 + s] = (s < 128) ? nh[m*SS + 192 + s] : nh2[m*SS + 64 + s];
}

// ---------------- attention sim: a=tanh(x@W+b); sim[m,h]=dot(a_head, c_head) -------
template<int D, int HD>
__global__ void k_att_sim(const float* __restrict__ x, const float* __restrict__ W,
                          const float* __restrict__ b, const float* __restrict__ c,
                          float* __restrict__ sim){
    int m0 = blockIdx.x*4, s = threadIdx.x;        // D threads
    __shared__ float xr[4][D];
    #pragma unroll
    for (int j=0;j<4;j++) xr[j][s] = x[(m0+j)*D + s];
    __syncthreads();
    float bias = b[s];
    float acc[4] = {bias,bias,bias,bias};
    for (int k=0;k<D;k++){
        float w = W[k*D + s];
        #pragma unroll
        for (int j=0;j<4;j++) acc[j] += xr[j][k]*w;
    }
    float cv = c[s];
    int h = s / HD;
    #pragma unroll
    for (int j=0;j<4;j++){
        float p = ftanh(acc[j])*cv;
        #pragma unroll
        for (int off=HD/2; off>0; off>>=1) p += __shfl_down(p, off);
        if ((s & (HD-1)) == 0) sim[(m0+j)*8 + h] = p;
    }
}

// ---------------- segment softmax (groups of 4 contiguous) + weighted sum ----------
template<int D, int HD>
__global__ void k_att_seg(const float* __restrict__ x, const float* __restrict__ sim,
                          float* __restrict__ out){
    int g = blockIdx.x, s = threadIdx.x;           // D threads
    __shared__ float wgt[4][8];
    if (s < 8){
        float v0 = sim[(g*4+0)*8+s], v1 = sim[(g*4+1)*8+s];
        float v2 = sim[(g*4+2)*8+s], v3 = sim[(g*4+3)*8+s];
        float mx = fmaxf(fmaxf(v0,v1), fmaxf(v2,v3));
        float e0 = __expf(v0-mx), e1 = __expf(v1-mx), e2 = __expf(v2-mx), e3 = __expf(v3-mx);
        float den = e0+e1+e2+e3;
        wgt[0][s]=e0/den; wgt[1][s]=e1/den; wgt[2][s]=e2/den; wgt[3][s]=e3/den;
    }
    __syncthreads();
    int h = s / HD;
    float o = 0.f;
    #pragma unroll
    for (int j=0;j<4;j++) o += x[(g*4+j)*D + s]*wgt[j][h];
    out[g*D + s] = o;
}

// ---------------- LSTM input pre-GEMM: g[t][gi] = b[gi] + wi[gi,:].x[t,:] ----------
template<int TIN, int G4>
__global__ void k_lstm_pre(const float* __restrict__ x,
        const float* __restrict__ wi_f, const float* __restrict__ b_f,
        const float* __restrict__ wi_b, const float* __restrict__ b_b,
        float* __restrict__ gf, float* __restrict__ gbo){
    int t0 = blockIdx.x*4, gi = threadIdx.x;       // G4 threads
    const float* wi = blockIdx.y ? wi_b : wi_f;
    const float* bb = blockIdx.y ? b_b  : b_f;
    float* go       = blockIdx.y ? gbo  : gf;
    __shared__ float xr[4][TIN];
    #pragma unroll
    for (int j=0;j<4;j++)
        for (int k=gi; k<TIN; k+=G4) xr[j][k] = x[(t0+j)*TIN + k];
    __syncthreads();
    float bv = bb[gi];
    float acc[4] = {bv,bv,bv,bv};
    const float* wrow = wi + (size_t)gi*TIN;
    for (int k=0;k<TIN;k++){
        float w = wrow[k];
        #pragma unroll
        for (int j=0;j<4;j++) acc[j] += xr[j][k]*w;
    }
    #pragma unroll
    for (int j=0;j<4;j++) go[(t0+j)*G4 + gi] = acc[j];
}

// ---------------- LSTM recurrence, H=64 T=256: reg weights, occupancy capped -------
#define DOT4(A,W,HV) { A += W.x*HV.x; A += W.y*HV.y; A += W.z*HV.z; A += W.w*HV.w; }
__global__ __launch_bounds__(256)
__attribute__((amdgpu_waves_per_eu(1, 1)))
void k_lstm_rec64(
        const float* __restrict__ gin_f, const float* __restrict__ wh_f,
        const float* __restrict__ gin_b, const float* __restrict__ wh_b,
        float* __restrict__ hid /* [T][128] */){
    const int H = 64, T = 256;
    int dir = blockIdx.x;
    const float* gin = dir ? gin_b : gin_f;
    const float* wh  = dir ? wh_b  : wh_f;
    int gi = threadIdx.x;                  // gate-row in [0, 256)
    const float4* wr = (const float4*)(wh + (size_t)gi*H);
    float4 w0=wr[0], w1=wr[1], w2=wr[2],  w3=wr[3],  w4=wr[4],  w5=wr[5],  w6=wr[6],  w7=wr[7];
    float4 w8=wr[8], w9=wr[9], w10=wr[10],w11=wr[11],w12=wr[12],w13=wr[13],w14=wr[14],w15=wr[15];
    __shared__ __align__(16) float hs[H];
    __shared__ float gsum[4*H];
    float c = 0.f;
    if (gi < H) hs[gi] = 0.f;
    __syncthreads();
    float gcur = gin[(dir ? (T-1) : 0)*4*H + gi];
    for (int step=0; step<T; step++){
        int t = dir ? (T-1-step) : step;
        float gnext = 0.f;
        if (step+1 < T) gnext = gin[(dir ? (T-2-step) : (step+1))*4*H + gi];
        const float4* hv = (const float4*)hs;      // uniform addr -> LDS broadcast
        float4 h0=hv[0], h1=hv[1], h2=hv[2],  h3=hv[3],  h4=hv[4],  h5=hv[5],  h6=hv[6],  h7=hv[7];
        float4 h8=hv[8], h9=hv[9], h10=hv[10],h11=hv[11],h12=hv[12],h13=hv[13],h14=hv[14],h15=hv[15];
        float a0 = gcur, a1 = 0.f, a2 = 0.f, a3 = 0.f;
        DOT4(a0,w0,h0)   DOT4(a1,w1,h1)   DOT4(a2,w2,h2)   DOT4(a3,w3,h3)
        DOT4(a0,w4,h4)   DOT4(a1,w5,h5)   DOT4(a2,w6,h6)   DOT4(a3,w7,h7)
        DOT4(a0,w8,h8)   DOT4(a1,w9,h9)   DOT4(a2,w10,h10) DOT4(a3,w11,h11)
        DOT4(a0,w12,h12) DOT4(a1,w13,h13) DOT4(a2,w14,h14) DOT4(a3,w15,h15)
        gsum[gi] = (a0+a1) + (a2+a3);
        __syncthreads();
        if (gi < H){
            float ig = gsum[gi], fg = gsum[H+gi], gg = gsum[2*H+gi], og = gsum[3*H+gi];
            c = fsig(fg)*c + fsig(ig)*ftanh(gg);
            float hn = fsig(og)*ftanh(c);
            hs[gi] = hn;
            hid[t*2*H + dir*H + gi] = hn;
        }
        __syncthreads();
        gcur = gnext;
    }
}

// ---------------- LSTM recurrence, H=32 T=64 ---------------------------------------
__global__ __launch_bounds__(128)
__attribute__((amdgpu_waves_per_eu(1, 1)))
void k_lstm_rec32(
        const float* __restrict__ gin_f, const float* __restrict__ wh_f,
        const float* __restrict__ gin_b, const float* __restrict__ wh_b,
        float* __restrict__ hid /* [T][64] */){
    const int H = 32, T = 64;
    int dir = blockIdx.x;
    const float* gin = dir ? gin_b : gin_f;
    const float* wh  = dir ? wh_b  : wh_f;
    int gi = threadIdx.x;                  // gate-row in [0, 128)
    const float4* wr = (const float4*)(wh + (size_t)gi*H);
    float4 w0=wr[0], w1=wr[1], w2=wr[2], w3=wr[3], w4=wr[4], w5=wr[5], w6=wr[6], w7=wr[7];
    __shared__ __align__(16) float hs[H];
    __shared__ float gsum[4*H];
    float c = 0.f;
    if (gi < H) hs[gi] = 0.f;
    __syncthreads();
    float gcur = gin[(dir ? (T-1) : 0)*4*H + gi];
    for (int step=0; step<T; step++){
        int t = dir ? (T-1-step) : step;
        float gnext = 0.f;
        if (step+1 < T) gnext = gin[(dir ? (T-2-step) : (step+1))*4*H + gi];
        const float4* hv = (const float4*)hs;
        float4 h0=hv[0], h1=hv[1], h2=hv[2], h3=hv[3], h4=hv[4], h5=hv[5], h6=hv[6], h7=hv[7];
        float a0 = gcur, a1 = 0.f, a2 = 0.f, a3 = 0.f;
        DOT4(a0,w0,h0) DOT4(a1,w1,h1) DOT4(a2,w2,h2) DOT4(a3,w3,h3)
        DOT4(a0,w4,h4) DOT4(a1,w5,h5) DOT4(a2,w6,h6) DOT4(a3,w7,h7)
        gsum[gi] = (a0+a1) + (a2+a3);
        __syncthreads();
        if (gi < H){
            float ig = gsum[gi], fg = gsum[H+gi], gg = gsum[2*H+gi], og = gsum[3*H+gi];
            c = fsig(fg)*c + fsig(ig)*ftanh(gg);
            float hn = fsig(og)*ftanh(c);
            hs[gi] = hn;
            hid[t*2*H + dir*H + gi] = hn;
        }
        __syncthreads();
        gcur = gnext;
    }
}

// ---------------- rebuild notes_hidden = [beat_span | meas_span | nh_sec] ----------
__global__ void k_spans(float* __restrict__ nhid, const float* __restrict__ bh,
                        const float* __restrict__ mh, const float* __restrict__ nh,
                        const int* __restrict__ bn, const int* __restrict__ mn){
    int n = blockIdx.x, s = threadIdx.x;           // 320 threads
    float v;
    if (s < 128)      v = bh[bn[n]*128 + s];
    else if (s < 192) v = mh[mn[n]*64 + (s-128)];
    else              v = nh[n*SS + s];
    nhid[n*SS + s] = v;
}

// ---------------- final output = [notes_hidden(320) | nh2_sec(128)] ----------------
__global__ void k_final(const float* __restrict__ nhid, const float* __restrict__ nh2,
                        float* __restrict__ out){
    int n = blockIdx.x, s = threadIdx.x;           // 448 threads
    out[n*448 + s] = (s < 320) ? nhid[n*SS + s] : nh2[n*SS + 192 + (s-320)];
}

// ===========================================================================
extern "C" void kernel_launch(void* const* d_in, const int* in_sizes, int n_in,
                              void* d_out, int out_size, void* d_ws, size_t ws_size,
                              hipStream_t stream) {
    const float* nodes    = (const float*)d_in[0];
    const float* adj      = (const float*)d_in[1];
    const int*   bn       = (const int*)  d_in[2];
    const int*   mn       = (const int*)  d_in[3];
    const float* fc_w     = (const float*)d_in[6];
    const float* fc_b     = (const float*)d_in[7];
    const float* g_wz[2]  = {(const float*)d_in[8],  (const float*)d_in[17]};
    const float* g_wr[2]  = {(const float*)d_in[9],  (const float*)d_in[18]};
    const float* g_wh[2]  = {(const float*)d_in[10], (const float*)d_in[19]};
    const float* g_uz[2]  = {(const float*)d_in[11], (const float*)d_in[20]};
    const float* g_ur[2]  = {(const float*)d_in[12], (const float*)d_in[21]};
    const float* g_uh[2]  = {(const float*)d_in[13], (const float*)d_in[22]};
    const float* g_bz[2]  = {(const float*)d_in[14], (const float*)d_in[23]};
    const float* g_br[2]  = {(const float*)d_in[15], (const float*)d_in[24]};
    const float* g_bh[2]  = {(const float*)d_in[16], (const float*)d_in[25]};
    const float* gb_w     = (const float*)d_in[26];
    const float* gb_b     = (const float*)d_in[27];
    const float* batt_w   = (const float*)d_in[28];
    const float* batt_b   = (const float*)d_in[29];
    const float* batt_c   = (const float*)d_in[30];
    const float* matt_w   = (const float*)d_in[31];
    const float* matt_b   = (const float*)d_in[32];
    const float* matt_c   = (const float*)d_in[33];
    const float* bwi_f    = (const float*)d_in[34];
    const float* bwh_f    = (const float*)d_in[35];
    const float* bb_f     = (const float*)d_in[36];
    const float* bwi_b    = (const float*)d_in[37];
    const float* bwh_b    = (const float*)d_in[38];
    const float* bb_b     = (const float*)d_in[39];
    const float* mwi_f    = (const float*)d_in[40];
    const float* mwh_f    = (const float*)d_in[41];
    const float* mb_f     = (const float*)d_in[42];
    const float* mwi_b    = (const float*)d_in[43];
    const float* mwh_b    = (const float*)d_in[44];
    const float* mb_b     = (const float*)d_in[45];
    float* out = (float*)d_out;

    // --- workspace layout (floats; total ~31 MB) ---
    float* W_   = (float*)d_ws;
    float* nhid = W_;                       // 1024*320
    float* nh   = nhid + 327680;            // 1024*320
    float* nh2  = nh   + 327680;            // 1024*320
    float* nb   = nh2  + 327680;            // 1024*320
    float* act  = nb   + 327680;            // 10*1024*320
    float* part = act  + 3276800;           // 5*1024*384
    float* cat  = part + 1966080;           // 1024*256
    float* sim  = cat  + 262144;            // 1024*8
    float* beat_nodes = sim + 8192;         // 256*256
    float* bgf  = beat_nodes + 65536;       // 256*256
    float* bgb  = bgf  + 65536;             // 256*256
    float* beat_hidden = bgb + 65536;       // 256*128
    float* msim = beat_hidden + 32768;      // 256*8
    float* meas_nodes = msim + 2048;        // 64*128
    float* mgf  = meas_nodes + 8192;        // 64*128
    float* mgb  = mgf  + 8192;              // 64*128
    float* meas_hidden = mgb + 8192;        // 64*64
    int*   cnt  = (int*)(meas_hidden + 4096);  // 10*1024
    int*   idx  = cnt + 10240;                  // 10*1024*64

    hipMemsetAsync(cnt, 0, EE*NN*sizeof(int), stream);
    k_csr_build<<<EE*NN, 256, 0, stream>>>(adj, cnt, idx);
    k_note_fc<<<NN, 128, 0, stream>>>(nodes, fc_w, fc_b, nhid);

    for (int si = 0; si < 2; ++si){
        hipMemcpyAsync(nh, nhid, (size_t)NN*SS*sizeof(float), hipMemcpyDeviceToDevice, stream);
        for (int it = 0; it < 2; ++it){
            k_gather_act<<<EE*NN, SS, 0, stream>>>(nh, cnt, idx, act);
            k_gate_gemm<<<dim3(16,3,5), 256, 0, stream>>>(act, g_wz[0], g_wr[0], g_wh[0], part);
            k_gru<<<NN/4, 128, 0, stream>>>(nh, part, g_uz[0], g_ur[0], g_uh[0],
                                            g_bz[0], g_br[0], g_bh[0]);
        }
        k_gb<<<NN/8, SS, 0, stream>>>(nh, gb_w, gb_b, nb);
        hipMemcpyAsync(nh2, nb, (size_t)NN*SS*sizeof(float), hipMemcpyDeviceToDevice, stream);
        for (int it = 0; it < 2; ++it){
            k_gather_act<<<EE*NN, SS, 0, stream>>>(nh2, cnt, idx, act);
            k_gate_gemm<<<dim3(16,3,5), 256, 0, stream>>>(act, g_wz[1], g_wr[1], g_wh[1], part);
            k_gru<<<NN/4, 128, 0, stream>>>(nh2, part, g_uz[1], g_ur[1], g_uh[1],
                                            g_bz[1], g_br[1], g_bh[1]);
        }
        k_build_cat<<<NN, 256, 0, stream>>>(nh, nh2, cat);
        k_att_sim<256,32><<<NN/4, 256, 0, stream>>>(cat, batt_w, batt_b, batt_c, sim);
        k_att_seg<256,32><<<NB, 256, 0, stream>>>(cat, sim, beat_nodes);
        k_lstm_pre<256,256><<<dim3(NB/4,2), 256, 0, stream>>>(beat_nodes, bwi_f, bb_f,
                                                              bwi_b, bb_b, bgf, bgb);
        k_lstm_rec64<<<2, 256, 0, stream>>>(bgf, bwh_f, bgb, bwh_b, beat_hidden);
        k_att_sim<128,16><<<NB/4, 128, 0, stream>>>(beat_hidden, matt_w, matt_b, matt_c, msim);
        k_att_seg<128,16><<<NM, 128, 0, stream>>>(beat_hidden, msim, meas_nodes);
        k_lstm_pre<128,128><<<dim3(NM/4,2), 128, 0, stream>>>(meas_nodes, mwi_f, mb_f,
                                                              mwi_b, mb_b, mgf, mgb);
        k_lstm_rec32<<<2, 128, 0, stream>>>(mgf, mwh_f, mgb, mwh_b, meas_hidden);
        k_spans<<<NN, SS, 0, stream>>>(nhid, beat_hidden, meas_hidden, nh, bn, mn);
    }
    k_final<<<NN, 448, 0, stream>>>(nhid, nh2, out);
}